// Round 6
// baseline (1065.093 us; speedup 1.0000x reference)
//
#include <hip/hip_runtime.h>
#include <hip/hip_bf16.h>
#include <math.h>

// CrystalGraphConvolution — MI355X round 6
// vs r5: step_fused = edge-GEMM (MFMA hi/lo) + sorted apply in ONE kernel with
// C-tile in LDS (C never touches HBM: -1.23 GB traffic, -1 kernel). B frags
// pre-packed once into a 64 KB plane buffer (bt_prep). node_mm keeps act/copy
// fusion. Sort machinery unchanged.

#define NN 50000
#define NE 800000
#define AD 128
#define ED 64
#define NSTEPS 3
#define NTILES (NE / 64)          // 12500
#define NSCAN  ((NN + 255) / 256) // 196

typedef __attribute__((ext_vector_type(8))) __bf16 bf16x8;
typedef __attribute__((ext_vector_type(4))) float  f32x4;
typedef __attribute__((ext_vector_type(2))) unsigned u32x2;

__device__ __forceinline__ float sigmoid_fast(float x) {
    float e = __expf(-fabsf(x));
    float r = __builtin_amdgcn_rcpf(1.f + e);
    return (x >= 0.f) ? r : 1.f - r;
}
__device__ __forceinline__ float softplus_fast(float x) {
    return fmaxf(x, 0.f) + __logf(1.f + __expf(-fabsf(x)));
}
__device__ __forceinline__ float msg_f(float s, float g) {
    return sigmoid_fast(s) * softplus_fast(g);
}
__device__ __forceinline__ float softplus_f(float x) {  // precise (output path)
    return fmaxf(x, 0.f) + log1pf(__expf(-fabsf(x)));
}
__device__ __forceinline__ unsigned short bf16_rne(float f) {
    unsigned u = __float_as_uint(f);
    unsigned r = u + 0x7fffu + ((u >> 16) & 1u);
    return (unsigned short)(r >> 16);
}
__device__ __forceinline__ unsigned pack_bf2(float s, float g) {
    return (unsigned)bf16_rne(s) | ((unsigned)bf16_rne(g) << 16);
}
__device__ __forceinline__ float unp_lo(unsigned v) { return __uint_as_float(v << 16); }
__device__ __forceinline__ float unp_hi(unsigned v) { return __uint_as_float(v & 0xffff0000u); }

// ===== node projections (bf16 packed PQ) + x maintenance =====
__global__ void __launch_bounds__(128) node_mm_b16(
    const float* __restrict__ xin, float* __restrict__ acc,
    const float* __restrict__ Ks, const float* __restrict__ Kg,
    unsigned* __restrict__ PQ32, int mode)
{
    __shared__ float xs[16][AD];
    const int t = threadIdx.x;
    const int row0 = blockIdx.x * 16;
    if (mode == 0) {
#pragma unroll
        for (int r = 0; r < 16; ++r) {
            float v = xin[(size_t)(row0 + r) * AD + t];
            xs[r][t] = v;
            acc[(size_t)(row0 + r) * AD + t] = v;
        }
    } else {
#pragma unroll
        for (int r = 0; r < 16; ++r) {
            float v = softplus_f(acc[(size_t)(row0 + r) * AD + t]);
            xs[r][t] = v;
            acc[(size_t)(row0 + r) * AD + t] = v;
        }
    }
    __syncthreads();

    float aPs[16] = {}, aQs[16] = {}, aPg[16] = {}, aQg[16] = {};
    for (int k4 = 0; k4 < AD / 4; ++k4) {
        const int k = 4 * k4;
        float ks_s[4], ks_d[4], kg_s[4], kg_d[4];
#pragma unroll
        for (int j = 0; j < 4; ++j) {
            ks_s[j] = Ks[(size_t)(k + j) * AD + t];
            ks_d[j] = Ks[(size_t)(AD + k + j) * AD + t];
            kg_s[j] = Kg[(size_t)(k + j) * AD + t];
            kg_d[j] = Kg[(size_t)(AD + k + j) * AD + t];
        }
#pragma unroll
        for (int r = 0; r < 16; ++r) {
            float4 xv = *(const float4*)&xs[r][k];
            aPs[r] = fmaf(xv.x, ks_s[0], aPs[r]);
            aPs[r] = fmaf(xv.y, ks_s[1], aPs[r]);
            aPs[r] = fmaf(xv.z, ks_s[2], aPs[r]);
            aPs[r] = fmaf(xv.w, ks_s[3], aPs[r]);
            aQs[r] = fmaf(xv.x, ks_d[0], aQs[r]);
            aQs[r] = fmaf(xv.y, ks_d[1], aQs[r]);
            aQs[r] = fmaf(xv.z, ks_d[2], aQs[r]);
            aQs[r] = fmaf(xv.w, ks_d[3], aQs[r]);
            aPg[r] = fmaf(xv.x, kg_s[0], aPg[r]);
            aPg[r] = fmaf(xv.y, kg_s[1], aPg[r]);
            aPg[r] = fmaf(xv.z, kg_s[2], aPg[r]);
            aPg[r] = fmaf(xv.w, kg_s[3], aPg[r]);
            aQg[r] = fmaf(xv.x, kg_d[0], aQg[r]);
            aQg[r] = fmaf(xv.y, kg_d[1], aQg[r]);
            aQg[r] = fmaf(xv.z, kg_d[2], aQg[r]);
            aQg[r] = fmaf(xv.w, kg_d[3], aQg[r]);
        }
    }
#pragma unroll
    for (int r = 0; r < 16; ++r) {
        unsigned* o = PQ32 + (size_t)(row0 + r) * 256;
        o[t]       = pack_bf2(aPs[r], aPg[r]);
        o[128 + t] = pack_bf2(aQs[r], aQg[r]);
    }
}

// ===== sort machinery =====
__global__ void __launch_bounds__(256) hist_k(const int* __restrict__ pidx,
                                              unsigned* __restrict__ cnt)
{
    int e = blockIdx.x * 256 + threadIdx.x;
    atomicAdd(&cnt[pidx[2 * e]], 1u);
}

__global__ void __launch_bounds__(256) scan1_k(const unsigned* __restrict__ cnt,
                                               unsigned* __restrict__ cur,
                                               unsigned* __restrict__ part)
{
    __shared__ unsigned tmp[256];
    const int t = threadIdx.x;
    const int bin = blockIdx.x * 256 + t;
    unsigned v = (bin < NN) ? cnt[bin] : 0u;
    tmp[t] = v;
    __syncthreads();
    for (int off = 1; off < 256; off <<= 1) {
        unsigned a = (t >= off) ? tmp[t - off] : 0u;
        __syncthreads();
        tmp[t] += a;
        __syncthreads();
    }
    if (bin < NN) cur[bin] = tmp[t] - v;
    if (t == 255) part[blockIdx.x] = tmp[255];
}

__global__ void __launch_bounds__(256) scan2_k(unsigned* __restrict__ part)
{
    __shared__ unsigned tmp[256];
    const int t = threadIdx.x;
    unsigned v = (t < NSCAN) ? part[t] : 0u;
    tmp[t] = v;
    __syncthreads();
    for (int off = 1; off < 256; off <<= 1) {
        unsigned a = (t >= off) ? tmp[t - off] : 0u;
        __syncthreads();
        tmp[t] += a;
        __syncthreads();
    }
    if (t < NSCAN) part[t] = tmp[t] - v;
}

__global__ void __launch_bounds__(256) scan3_k(unsigned* __restrict__ cur,
                                               const unsigned* __restrict__ part)
{
    const int bin = blockIdx.x * 256 + threadIdx.x;
    if (bin < NN) cur[bin] += part[blockIdx.x];
}

__global__ void __launch_bounds__(256) scatter_k(
    const int* __restrict__ pidx, unsigned* __restrict__ cur,
    int* __restrict__ sid, int* __restrict__ ssrc, int* __restrict__ sdst)
{
    int e = blockIdx.x * 256 + threadIdx.x;
    int s = pidx[2 * e], d = pidx[2 * e + 1];
    unsigned pos = atomicAdd(&cur[s], 1u);
    sid[pos] = e;
    ssrc[pos] = s;
    sdst[pos] = d;
}

// ===== one-time B fragment pre-pack =====
// Bt vector index: (((m*2 + hl)*2 + ki)*128 + col)*4 + l4  (4096 x bf16x8 = 64 KB)
// element j of that vector = K_m[2*AD + ki*32 + l4*8 + j][col], hi or lo plane.
__global__ void __launch_bounds__(256) bt_prep(
    const float* __restrict__ Ks, const float* __restrict__ Kg,
    bf16x8* __restrict__ Bt)
{
    union U8 { short s[8]; bf16x8 v; };
    for (int idx = threadIdx.x; idx < 4096; idx += 256) {
        int l4  = idx & 3;
        int col = (idx >> 2) & 127;
        int ki  = (idx >> 9) & 1;
        int hl  = (idx >> 10) & 1;
        int m   = (idx >> 11) & 1;
        const float* K = m ? Kg : Ks;
        U8 o;
#pragma unroll
        for (int j = 0; j < 8; ++j) {
            int k = ki * 32 + l4 * 8 + j;
            float v = K[(size_t)(2 * AD + k) * AD + col];
            unsigned short h = bf16_rne(v);
            if (hl == 0) o.s[j] = (short)h;
            else o.s[j] = (short)bf16_rne(v - __uint_as_float((unsigned)h << 16));
        }
        Bt[idx] = o.v;
    }
}

// ===== fused per-step kernel: MFMA C-tile in LDS + sorted apply =====
#define FXR(row) ((((row) >> 2) & 3) << 3)   // Ctile col-XOR swizzle

__global__ void __launch_bounds__(256) step_fused(
    const float* __restrict__ ef, const bf16x8* __restrict__ Bt,
    const int* __restrict__ sid, const int* __restrict__ ssrc,
    const int* __restrict__ sdst, const u32x2* __restrict__ PQ64,
    const float* __restrict__ bs, const float* __restrict__ bg,
    float* __restrict__ acc)
{
    __shared__ short As_h[64 * 64];
    __shared__ short As_l[64 * 64];
    __shared__ unsigned Ctile[64 * 128];   // packed (s,g) bf16, col-swizzled
    __shared__ int s_src[64], s_dst[64];

    const int t = threadIdx.x;
    const int w = t >> 6, lane = t & 63;
    const size_t p0 = (size_t)blockIdx.x * 64;

    if (t < 64) { s_src[t] = ssrc[p0 + t]; s_dst[t] = sdst[p0 + t]; }

    // ---- stage A (gather ef rows via sid, hi/lo split, swizzled LDS) ----
#pragma unroll
    for (int ii = 0; ii < 4; ++ii) {
        int i = t + 256 * ii, row = i >> 4, c4 = i & 15;
        int e = sid[p0 + row];
        float4 v = *(const float4*)&ef[(size_t)e * 64 + 4 * c4];
        unsigned short h0 = bf16_rne(v.x), h1 = bf16_rne(v.y),
                       h2 = bf16_rne(v.z), h3 = bf16_rne(v.w);
        unsigned short l0 = bf16_rne(v.x - __uint_as_float((unsigned)h0 << 16));
        unsigned short l1 = bf16_rne(v.y - __uint_as_float((unsigned)h1 << 16));
        unsigned short l2 = bf16_rne(v.z - __uint_as_float((unsigned)h2 << 16));
        unsigned short l3 = bf16_rne(v.w - __uint_as_float((unsigned)h3 << 16));
        int sidx = (row * 64 + c4 * 4) ^ ((row & 7) << 3);
        *(short4*)&As_h[sidx] = make_short4((short)h0, (short)h1, (short)h2, (short)h3);
        *(short4*)&As_l[sidx] = make_short4((short)l0, (short)l1, (short)l2, (short)l3);
    }
    __syncthreads();

    // ---- MFMA: wave w covers cols (2w+p)*16 + (lane&15), p in {0,1} ----
    const int l4 = lane >> 4;
#pragma unroll
    for (int p = 0; p < 2; ++p) {
        const int col = (2 * w + p) * 16 + (lane & 15);
        const int vb = col * 4 + l4;
        bf16x8 bSh[2], bSl[2], bGh[2], bGl[2];
#pragma unroll
        for (int ki = 0; ki < 2; ++ki) {
            bSh[ki] = Bt[(0 * 2 + ki) * 512 + vb];        // m=0 hl=0
            bSl[ki] = Bt[(1 * 2 + ki) * 512 + vb];        // m=0 hl=1
            bGh[ki] = Bt[(2 * 2 + ki) * 512 + vb];        // m=1 hl=0
            bGl[ki] = Bt[(3 * 2 + ki) * 512 + vb];        // m=1 hl=1
        }
        f32x4 aS[4] = {}, aG[4] = {};
#pragma unroll
        for (int mt = 0; mt < 4; ++mt) {
#pragma unroll
            for (int ki = 0; ki < 2; ++ki) {
                int row = mt * 16 + (lane & 15);
                int idx = (row * 64 + ki * 32 + l4 * 8) ^ ((row & 7) << 3);
                bf16x8 ah = *(const bf16x8*)&As_h[idx];
                bf16x8 al = *(const bf16x8*)&As_l[idx];
                aS[mt] = __builtin_amdgcn_mfma_f32_16x16x32_bf16(ah, bSh[ki], aS[mt], 0, 0, 0);
                aS[mt] = __builtin_amdgcn_mfma_f32_16x16x32_bf16(al, bSh[ki], aS[mt], 0, 0, 0);
                aS[mt] = __builtin_amdgcn_mfma_f32_16x16x32_bf16(ah, bSl[ki], aS[mt], 0, 0, 0);
                aG[mt] = __builtin_amdgcn_mfma_f32_16x16x32_bf16(ah, bGh[ki], aG[mt], 0, 0, 0);
                aG[mt] = __builtin_amdgcn_mfma_f32_16x16x32_bf16(al, bGh[ki], aG[mt], 0, 0, 0);
                aG[mt] = __builtin_amdgcn_mfma_f32_16x16x32_bf16(ah, bGl[ki], aG[mt], 0, 0, 0);
            }
        }
#pragma unroll
        for (int mt = 0; mt < 4; ++mt) {
#pragma unroll
            for (int reg = 0; reg < 4; ++reg) {
                int row = mt * 16 + l4 * 4 + reg;
                Ctile[row * 128 + (col ^ FXR(row))] = pack_bf2(aS[mt][reg], aG[mt][reg]);
            }
        }
    }
    __syncthreads();

    // ---- sorted apply: wave w handles edges e0..e0+15, lane lt = 2 channels ----
    const int lt = lane;
    const int e0 = w * 16;
    const float2 bsv = *(const float2*)&bs[2 * lt];
    const float2 bgv = *(const float2*)&bg[2 * lt];

    int cur = s_src[e0];
    u32x2 pv = PQ64[(size_t)cur * 128 + lt];
    float psA = unp_lo(pv.x) + bsv.x, pgA = unp_hi(pv.x) + bgv.x;
    float psB = unp_lo(pv.y) + bsv.y, pgB = unp_hi(pv.y) + bgv.y;

    u32x2 q0 = PQ64[(size_t)s_dst[e0 + 0] * 128 + 64 + lt];
    u32x2 q1 = PQ64[(size_t)s_dst[e0 + 1] * 128 + 64 + lt];
    u32x2 q2 = PQ64[(size_t)s_dst[e0 + 2] * 128 + 64 + lt];
    u32x2 q3 = PQ64[(size_t)s_dst[e0 + 3] * 128 + 64 + lt];
    u32x2 r0 = pv, r1 = pv, r2 = pv, r3 = pv;
    if (s_src[e0 + 1] != s_src[e0 + 0]) r1 = PQ64[(size_t)s_src[e0 + 1] * 128 + lt];
    if (s_src[e0 + 2] != s_src[e0 + 1]) r2 = PQ64[(size_t)s_src[e0 + 2] * 128 + lt];
    if (s_src[e0 + 3] != s_src[e0 + 2]) r3 = PQ64[(size_t)s_src[e0 + 3] * 128 + lt];
    float accA = 0.f, accB = 0.f;

#define PROC_CORE(i, qq, rr)                                               \
    {                                                                      \
        int row_ = e0 + (i);                                               \
        u32x2 cc = *(const u32x2*)&Ctile[row_ * 128 + ((2 * lt) ^ FXR(row_))]; \
        int src_ = s_src[row_];                                            \
        if (src_ != cur) {                                                 \
            atomicAdd(&acc[(size_t)cur * AD + 2 * lt],     accA);          \
            atomicAdd(&acc[(size_t)cur * AD + 2 * lt + 1], accB);          \
            accA = 0.f; accB = 0.f; cur = src_;                            \
            psA = unp_lo(rr.x) + bsv.x; pgA = unp_hi(rr.x) + bgv.x;        \
            psB = unp_lo(rr.y) + bsv.y; pgB = unp_hi(rr.y) + bgv.y;        \
        }                                                                  \
        float sA = unp_lo(cc.x) + unp_lo(qq.x) + psA;                      \
        float gA = unp_hi(cc.x) + unp_hi(qq.x) + pgA;                      \
        float sB = unp_lo(cc.y) + unp_lo(qq.y) + psB;                      \
        float gB = unp_hi(cc.y) + unp_hi(qq.y) + pgB;                      \
        accA += msg_f(sA, gA);                                             \
        accB += msg_f(sB, gB);                                             \
    }

#define PROC(i, qq, rr)                                                    \
    PROC_CORE(i, qq, rr)                                                   \
    {                                                                      \
        int nx_ = e0 + (i) + 4;                                            \
        qq = PQ64[(size_t)s_dst[nx_] * 128 + 64 + lt];                     \
        if (s_src[nx_] != s_src[nx_ - 1])                                  \
            rr = PQ64[(size_t)s_src[nx_] * 128 + lt];                      \
    }

    for (int j = 0; j < 3; ++j) {
        int b = 4 * j;
        PROC(b + 0, q0, r0)
        PROC(b + 1, q1, r1)
        PROC(b + 2, q2, r2)
        PROC(b + 3, q3, r3)
    }
    PROC_CORE(12, q0, r0)
    PROC_CORE(13, q1, r1)
    PROC_CORE(14, q2, r2)
    PROC_CORE(15, q3, r3)

    atomicAdd(&acc[(size_t)cur * AD + 2 * lt],     accA);
    atomicAdd(&acc[(size_t)cur * AD + 2 * lt + 1], accB);
#undef PROC
#undef PROC_CORE
}

// ===== final softplus =====
__global__ void __launch_bounds__(256) act_k(float* __restrict__ acc)
{
    size_t i = ((size_t)blockIdx.x * 256 + threadIdx.x) * 4;
    float4 v = *(float4*)&acc[i];
    v.x = softplus_f(v.x);
    v.y = softplus_f(v.y);
    v.z = softplus_f(v.z);
    v.w = softplus_f(v.w);
    *(float4*)&acc[i] = v;
}

// ===== Tier B fallback (round-1, known good) =====
__global__ void __launch_bounds__(128) node_mm_f32(
    const float* __restrict__ x, const float* __restrict__ Ks,
    const float* __restrict__ Kg, float* __restrict__ PQ)
{
    __shared__ float xs[8][AD];
    const int t = threadIdx.x;
    const int row0 = blockIdx.x * 8;
#pragma unroll
    for (int r = 0; r < 8; ++r) xs[r][t] = x[(size_t)(row0 + r) * AD + t];
    __syncthreads();
    float aPs[8] = {}, aQs[8] = {}, aPg[8] = {}, aQg[8] = {};
    for (int k = 0; k < AD; ++k) {
        float ks_s = Ks[k * AD + t];
        float ks_d = Ks[(AD + k) * AD + t];
        float kg_s = Kg[k * AD + t];
        float kg_d = Kg[(AD + k) * AD + t];
#pragma unroll
        for (int r = 0; r < 8; ++r) {
            float xv = xs[r][k];
            aPs[r] = fmaf(xv, ks_s, aPs[r]);
            aQs[r] = fmaf(xv, ks_d, aQs[r]);
            aPg[r] = fmaf(xv, kg_s, aPg[r]);
            aQg[r] = fmaf(xv, kg_d, aQg[r]);
        }
    }
#pragma unroll
    for (int r = 0; r < 8; ++r) {
        float* o = PQ + (size_t)(row0 + r) * 512;
        *(float2*)&o[2 * t]       = make_float2(aPs[r], aPg[r]);
        *(float2*)&o[256 + 2 * t] = make_float2(aQs[r], aQg[r]);
    }
}

__global__ void __launch_bounds__(256) edge_fused(
    const float* __restrict__ ef, const float* __restrict__ Ks,
    const float* __restrict__ Kg, const float* __restrict__ PQ,
    const int* __restrict__ pidx, const float* __restrict__ bs,
    const float* __restrict__ bg, float* __restrict__ acc)
{
    __shared__ float KB[ED][2 * AD];
    __shared__ float es[64][ED];
    const int t = threadIdx.x;
    for (int i = t; i < ED * AD; i += 256) {
        int k = i >> 7, n = i & 127;
        KB[k][2 * n]     = Ks[(2 * AD + k) * AD + n];
        KB[k][2 * n + 1] = Kg[(2 * AD + k) * AD + n];
    }
    const size_t e0 = (size_t)blockIdx.x * 64;
    for (int i = t; i < 64 * ED; i += 256) ((float*)es)[i] = ef[e0 * ED + i];
    __syncthreads();
    const int le = t >> 7, n = t & 127;
    const float bsn = bs[n], bgn = bg[n];
    for (int base = le * 8; base < 64; base += 16) {
        float accS[8] = {}, accG[8] = {};
        for (int k4 = 0; k4 < ED / 4; ++k4) {
            float2 kv0 = *(const float2*)&KB[4 * k4 + 0][2 * n];
            float2 kv1 = *(const float2*)&KB[4 * k4 + 1][2 * n];
            float2 kv2 = *(const float2*)&KB[4 * k4 + 2][2 * n];
            float2 kv3 = *(const float2*)&KB[4 * k4 + 3][2 * n];
#pragma unroll
            for (int r = 0; r < 8; ++r) {
                float4 ev = *(const float4*)&es[base + r][4 * k4];
                accS[r] = fmaf(ev.x, kv0.x, accS[r]);
                accG[r] = fmaf(ev.x, kv0.y, accG[r]);
                accS[r] = fmaf(ev.y, kv1.x, accS[r]);
                accG[r] = fmaf(ev.y, kv1.y, accG[r]);
                accS[r] = fmaf(ev.z, kv2.x, accS[r]);
                accG[r] = fmaf(ev.z, kv2.y, accG[r]);
                accS[r] = fmaf(ev.w, kv3.x, accS[r]);
                accG[r] = fmaf(ev.w, kv3.y, accG[r]);
            }
        }
#pragma unroll
        for (int r = 0; r < 8; ++r) {
            size_t e = e0 + base + r;
            int src = pidx[2 * e], dst = pidx[2 * e + 1];
            float2 pv = *(const float2*)&PQ[(size_t)src * 512 + 2 * n];
            float2 qv = *(const float2*)&PQ[(size_t)dst * 512 + 256 + 2 * n];
            float s = accS[r] + pv.x + qv.x + bsn;
            float g = accG[r] + pv.y + qv.y + bgn;
            atomicAdd(&acc[(size_t)src * AD + n], sigmoid_fast(s) * softplus_f(g));
        }
    }
}

// ===== launch =====
extern "C" void kernel_launch(void* const* d_in, const int* in_sizes, int n_in,
                              void* d_out, int out_size, void* d_ws, size_t ws_size,
                              hipStream_t stream)
{
    const float* atom = (const float*)d_in[0];
    const float* ef   = (const float*)d_in[1];
    const float* Ks   = (const float*)d_in[3];
    const float* bs   = (const float*)d_in[4];
    const float* Kg   = (const float*)d_in[5];
    const float* bg   = (const float*)d_in[6];
    const int*   pidx = (const int*)d_in[7];

    float* acc = (float*)d_out;

    char* w = (char*)d_ws;
    const size_t PQ_B   = (size_t)NN * 256 * 4;   //  51.2 MB
    const size_t BT_B   = 4096 * 16;              //  64 KB
    const size_t CNT_B  = (size_t)NN * 4;
    const size_t IDX_B  = (size_t)NE * 4;
    const size_t PART_B = 256 * 4;
    unsigned* PQ32 = (unsigned*)w;  w += PQ_B;
    bf16x8*   Bt   = (bf16x8*)w;    w += BT_B;
    unsigned* cnt  = (unsigned*)w;  w += CNT_B;
    unsigned* curp = (unsigned*)w;  w += CNT_B;
    int*      sid  = (int*)w;       w += IDX_B;
    int*      ssrc = (int*)w;       w += IDX_B;
    int*      sdst = (int*)w;       w += IDX_B;
    unsigned* part = (unsigned*)w;  w += PART_B;
    const size_t TOTAL_A = PQ_B + BT_B + 2 * CNT_B + 3 * IDX_B + PART_B;

    if (ws_size >= TOTAL_A) {
        hipMemsetAsync(cnt, 0, CNT_B, stream);
        bt_prep<<<1, 256, 0, stream>>>(Ks, Kg, Bt);
        hist_k<<<NE / 256, 256, 0, stream>>>(pidx, cnt);
        scan1_k<<<NSCAN, 256, 0, stream>>>(cnt, curp, part);
        scan2_k<<<1, 256, 0, stream>>>(part);
        scan3_k<<<NSCAN, 256, 0, stream>>>(curp, part);
        scatter_k<<<NE / 256, 256, 0, stream>>>(pidx, curp, sid, ssrc, sdst);

        for (int s = 0; s < NSTEPS; ++s) {
            node_mm_b16<<<NN / 16, 128, 0, stream>>>(atom, acc, Ks, Kg, PQ32,
                                                     s == 0 ? 0 : 1);
            step_fused<<<NTILES, 256, 0, stream>>>(ef, Bt, sid, ssrc, sdst,
                                                   (const u32x2*)PQ32, bs, bg, acc);
        }
        act_k<<<(NN * AD) / 1024, 256, 0, stream>>>(acc);
    } else {
        float* PQ = (float*)d_ws;
        hipMemcpyAsync(acc, atom, (size_t)NN * AD * sizeof(float),
                       hipMemcpyDeviceToDevice, stream);
        for (int s = 0; s < NSTEPS; ++s) {
            node_mm_f32<<<NN / 8, 128, 0, stream>>>(acc, Ks, Kg, PQ);
            edge_fused<<<NE / 64, 256, 0, stream>>>(ef, Ks, Kg, PQ, pidx, bs, bg, acc);
            act_k<<<(NN * AD) / 1024, 256, 0, stream>>>(acc);
        }
    }
}

// Round 7
// 994.556 us; speedup vs baseline: 1.0709x; 1.0709x over previous
//
#include <hip/hip_runtime.h>
#include <hip/hip_bf16.h>
#include <math.h>

// CrystalGraphConvolution — MI355X round 7
// r6 fusion regressed -> revert to r5 structure (C computed once, streamed 3x).
// vs r5: edge_c grid 1024 (4 blk/CU), nontemporal ef gather; apply VALU diet
// (branch-free sigmoid, fmaf accum, pre-scaled byte offsets from scatter_k).

#define NN 50000
#define NE 800000
#define AD 128
#define ED 64
#define NSTEPS 3
#define NTILES (NE / 64)          // 12500
#define NSCAN  ((NN + 255) / 256) // 196

typedef __attribute__((ext_vector_type(8))) __bf16 bf16x8;
typedef __attribute__((ext_vector_type(4))) float  f32x4;
typedef __attribute__((ext_vector_type(2))) unsigned u32x2;

__device__ __forceinline__ float sigmoid_nb(float x) {      // branch-free
    return __builtin_amdgcn_rcpf(1.f + __expf(-x));         // -inf->0, +inf->1
}
__device__ __forceinline__ float softplus_fast(float x) {
    return fmaxf(x, 0.f) + __logf(1.f + __expf(-fabsf(x)));
}
__device__ __forceinline__ float softplus_f(float x) {      // precise (output path)
    return fmaxf(x, 0.f) + log1pf(__expf(-fabsf(x)));
}
__device__ __forceinline__ float sigmoid_fast(float x) {    // Tier B
    float e = __expf(-fabsf(x));
    float r = __builtin_amdgcn_rcpf(1.f + e);
    return (x >= 0.f) ? r : 1.f - r;
}
__device__ __forceinline__ unsigned short bf16_rne(float f) {
    unsigned u = __float_as_uint(f);
    unsigned r = u + 0x7fffu + ((u >> 16) & 1u);
    return (unsigned short)(r >> 16);
}
__device__ __forceinline__ unsigned pack_bf2(float s, float g) {
    return (unsigned)bf16_rne(s) | ((unsigned)bf16_rne(g) << 16);
}
__device__ __forceinline__ float unp_lo(unsigned v) { return __uint_as_float(v << 16); }
__device__ __forceinline__ float unp_hi(unsigned v) { return __uint_as_float(v & 0xffff0000u); }

// ===== node projections (bf16 packed PQ) + x maintenance =====
__global__ void __launch_bounds__(128) node_mm_b16(
    const float* __restrict__ xin, float* __restrict__ acc,
    const float* __restrict__ Ks, const float* __restrict__ Kg,
    unsigned* __restrict__ PQ32, int mode)
{
    __shared__ float xs[16][AD];
    const int t = threadIdx.x;
    const int row0 = blockIdx.x * 16;
    if (mode == 0) {
#pragma unroll
        for (int r = 0; r < 16; ++r) {
            float v = xin[(size_t)(row0 + r) * AD + t];
            xs[r][t] = v;
            acc[(size_t)(row0 + r) * AD + t] = v;
        }
    } else {
#pragma unroll
        for (int r = 0; r < 16; ++r) {
            float v = softplus_f(acc[(size_t)(row0 + r) * AD + t]);
            xs[r][t] = v;
            acc[(size_t)(row0 + r) * AD + t] = v;
        }
    }
    __syncthreads();

    float aPs[16] = {}, aQs[16] = {}, aPg[16] = {}, aQg[16] = {};
    for (int k4 = 0; k4 < AD / 4; ++k4) {
        const int k = 4 * k4;
        float ks_s[4], ks_d[4], kg_s[4], kg_d[4];
#pragma unroll
        for (int j = 0; j < 4; ++j) {
            ks_s[j] = Ks[(size_t)(k + j) * AD + t];
            ks_d[j] = Ks[(size_t)(AD + k + j) * AD + t];
            kg_s[j] = Kg[(size_t)(k + j) * AD + t];
            kg_d[j] = Kg[(size_t)(AD + k + j) * AD + t];
        }
#pragma unroll
        for (int r = 0; r < 16; ++r) {
            float4 xv = *(const float4*)&xs[r][k];
            aPs[r] = fmaf(xv.x, ks_s[0], aPs[r]);
            aPs[r] = fmaf(xv.y, ks_s[1], aPs[r]);
            aPs[r] = fmaf(xv.z, ks_s[2], aPs[r]);
            aPs[r] = fmaf(xv.w, ks_s[3], aPs[r]);
            aQs[r] = fmaf(xv.x, ks_d[0], aQs[r]);
            aQs[r] = fmaf(xv.y, ks_d[1], aQs[r]);
            aQs[r] = fmaf(xv.z, ks_d[2], aQs[r]);
            aQs[r] = fmaf(xv.w, ks_d[3], aQs[r]);
            aPg[r] = fmaf(xv.x, kg_s[0], aPg[r]);
            aPg[r] = fmaf(xv.y, kg_s[1], aPg[r]);
            aPg[r] = fmaf(xv.z, kg_s[2], aPg[r]);
            aPg[r] = fmaf(xv.w, kg_s[3], aPg[r]);
            aQg[r] = fmaf(xv.x, kg_d[0], aQg[r]);
            aQg[r] = fmaf(xv.y, kg_d[1], aQg[r]);
            aQg[r] = fmaf(xv.z, kg_d[2], aQg[r]);
            aQg[r] = fmaf(xv.w, kg_d[3], aQg[r]);
        }
    }
#pragma unroll
    for (int r = 0; r < 16; ++r) {
        unsigned* o = PQ32 + (size_t)(row0 + r) * 256;
        o[t]       = pack_bf2(aPs[r], aPg[r]);
        o[128 + t] = pack_bf2(aQs[r], aQg[r]);
    }
}

// ===== sort machinery =====
__global__ void __launch_bounds__(256) hist_k(const int* __restrict__ pidx,
                                              unsigned* __restrict__ cnt)
{
    int e = blockIdx.x * 256 + threadIdx.x;
    atomicAdd(&cnt[pidx[2 * e]], 1u);
}

__global__ void __launch_bounds__(256) scan1_k(const unsigned* __restrict__ cnt,
                                               unsigned* __restrict__ cur,
                                               unsigned* __restrict__ part)
{
    __shared__ unsigned tmp[256];
    const int t = threadIdx.x;
    const int bin = blockIdx.x * 256 + t;
    unsigned v = (bin < NN) ? cnt[bin] : 0u;
    tmp[t] = v;
    __syncthreads();
    for (int off = 1; off < 256; off <<= 1) {
        unsigned a = (t >= off) ? tmp[t - off] : 0u;
        __syncthreads();
        tmp[t] += a;
        __syncthreads();
    }
    if (bin < NN) cur[bin] = tmp[t] - v;
    if (t == 255) part[blockIdx.x] = tmp[255];
}

__global__ void __launch_bounds__(256) scan2_k(unsigned* __restrict__ part)
{
    __shared__ unsigned tmp[256];
    const int t = threadIdx.x;
    unsigned v = (t < NSCAN) ? part[t] : 0u;
    tmp[t] = v;
    __syncthreads();
    for (int off = 1; off < 256; off <<= 1) {
        unsigned a = (t >= off) ? tmp[t - off] : 0u;
        __syncthreads();
        tmp[t] += a;
        __syncthreads();
    }
    if (t < NSCAN) part[t] = tmp[t] - v;
}

__global__ void __launch_bounds__(256) scan3_k(unsigned* __restrict__ cur,
                                               const unsigned* __restrict__ part)
{
    const int bin = blockIdx.x * 256 + threadIdx.x;
    if (bin < NN) cur[bin] += part[blockIdx.x];
}

// scaled offsets: ssrc = src*1024 (P byte off), sdst = dst*1024+512 (Q byte off)
__global__ void __launch_bounds__(256) scatter_k(
    const int* __restrict__ pidx, unsigned* __restrict__ cur,
    int* __restrict__ sid, int* __restrict__ ssrc, int* __restrict__ sdst)
{
    int e = blockIdx.x * 256 + threadIdx.x;
    int s = pidx[2 * e], d = pidx[2 * e + 1];
    unsigned pos = atomicAdd(&cur[s], 1u);
    sid[pos] = e;
    ssrc[pos] = s << 10;
    sdst[pos] = (d << 10) + 512;
}

// ===== C = ef @ K_bot via MFMA (hi/lo split), gather-read / linear-write =====
__global__ void __launch_bounds__(512) edge_c_mfma(
    const float* __restrict__ ef, const float* __restrict__ Ks,
    const float* __restrict__ Kg, const int* __restrict__ sid,
    unsigned* __restrict__ C32)
{
    __shared__ short As_h[64 * 64];
    __shared__ short As_l[64 * 64];
    const int t = threadIdx.x;
    const int w = t >> 6, lane = t & 63;

    union U8 { short s[8]; bf16x8 v; };
    bf16x8 bS[2][2], bG[2][2];   // [ki][hi/lo]
    {
        const int col = w * 16 + (lane & 15);
#pragma unroll
        for (int ki = 0; ki < 2; ++ki) {
            U8 sh_, sl_, gh_, gl_;
            const int kbase = 2 * AD + ki * 32 + (lane >> 4) * 8;
#pragma unroll
            for (int j = 0; j < 8; ++j) {
                float vs = Ks[(size_t)(kbase + j) * AD + col];
                float vg = Kg[(size_t)(kbase + j) * AD + col];
                unsigned short h = bf16_rne(vs);
                sh_.s[j] = (short)h;
                sl_.s[j] = (short)bf16_rne(vs - __uint_as_float((unsigned)h << 16));
                h = bf16_rne(vg);
                gh_.s[j] = (short)h;
                gl_.s[j] = (short)bf16_rne(vg - __uint_as_float((unsigned)h << 16));
            }
            bS[ki][0] = sh_.v; bS[ki][1] = sl_.v;
            bG[ki][0] = gh_.v; bG[ki][1] = gl_.v;
        }
    }

    const int srow = t >> 4, sc4 = t & 15;
    f32x4 pf0, pf1;
    {
        int ea = sid[(size_t)blockIdx.x * 64 + srow];
        int eb = sid[(size_t)blockIdx.x * 64 + srow + 32];
        pf0 = __builtin_nontemporal_load((const f32x4*)&ef[(size_t)ea * 64 + 4 * sc4]);
        pf1 = __builtin_nontemporal_load((const f32x4*)&ef[(size_t)eb * 64 + 4 * sc4]);
    }

    for (int tile = blockIdx.x; tile < NTILES; tile += gridDim.x) {
        __syncthreads();
        {
            f32x4 v[2] = {pf0, pf1};
#pragma unroll
            for (int ii = 0; ii < 2; ++ii) {
                int row = srow + 32 * ii;
                float a0 = v[ii][0], a1 = v[ii][1], a2 = v[ii][2], a3 = v[ii][3];
                unsigned short h0 = bf16_rne(a0), h1 = bf16_rne(a1),
                               h2 = bf16_rne(a2), h3 = bf16_rne(a3);
                unsigned short l0 = bf16_rne(a0 - __uint_as_float((unsigned)h0 << 16));
                unsigned short l1 = bf16_rne(a1 - __uint_as_float((unsigned)h1 << 16));
                unsigned short l2 = bf16_rne(a2 - __uint_as_float((unsigned)h2 << 16));
                unsigned short l3 = bf16_rne(a3 - __uint_as_float((unsigned)h3 << 16));
                int sidx = (row * 64 + sc4 * 4) ^ ((row & 7) << 3);
                *(short4*)&As_h[sidx] = make_short4((short)h0, (short)h1, (short)h2, (short)h3);
                *(short4*)&As_l[sidx] = make_short4((short)l0, (short)l1, (short)l2, (short)l3);
            }
        }
        {
            int nxt = tile + gridDim.x;
            if (nxt < NTILES) {
                int ea = sid[(size_t)nxt * 64 + srow];
                int eb = sid[(size_t)nxt * 64 + srow + 32];
                pf0 = __builtin_nontemporal_load((const f32x4*)&ef[(size_t)ea * 64 + 4 * sc4]);
                pf1 = __builtin_nontemporal_load((const f32x4*)&ef[(size_t)eb * 64 + 4 * sc4]);
            }
        }
        __syncthreads();

        f32x4 accS[4] = {}, accG[4] = {};
#pragma unroll
        for (int mt = 0; mt < 4; ++mt) {
#pragma unroll
            for (int ki = 0; ki < 2; ++ki) {
                int row = mt * 16 + (lane & 15);
                int idx = (row * 64 + ki * 32 + (lane >> 4) * 8) ^ ((row & 7) << 3);
                bf16x8 ah = *(const bf16x8*)&As_h[idx];
                bf16x8 al = *(const bf16x8*)&As_l[idx];
                accS[mt] = __builtin_amdgcn_mfma_f32_16x16x32_bf16(ah, bS[ki][0], accS[mt], 0, 0, 0);
                accS[mt] = __builtin_amdgcn_mfma_f32_16x16x32_bf16(al, bS[ki][0], accS[mt], 0, 0, 0);
                accS[mt] = __builtin_amdgcn_mfma_f32_16x16x32_bf16(ah, bS[ki][1], accS[mt], 0, 0, 0);
                accG[mt] = __builtin_amdgcn_mfma_f32_16x16x32_bf16(ah, bG[ki][0], accG[mt], 0, 0, 0);
                accG[mt] = __builtin_amdgcn_mfma_f32_16x16x32_bf16(al, bG[ki][0], accG[mt], 0, 0, 0);
                accG[mt] = __builtin_amdgcn_mfma_f32_16x16x32_bf16(ah, bG[ki][1], accG[mt], 0, 0, 0);
            }
        }
        const size_t p0 = (size_t)tile * 64;
#pragma unroll
        for (int mt = 0; mt < 4; ++mt) {
#pragma unroll
            for (int reg = 0; reg < 4; ++reg) {
                int row = mt * 16 + (lane >> 4) * 4 + reg;
                unsigned val = pack_bf2(accS[mt][reg], accG[mt][reg]);
                __builtin_nontemporal_store(val,
                    &C32[(p0 + row) * 128 + w * 16 + (lane & 15)]);
            }
        }
    }
}

// ===== sorted apply v3: byte-offset addressing, branch-free sigmoid =====
__global__ void __launch_bounds__(256) edge_apply_sorted(
    const char* __restrict__ C8, const char* __restrict__ PQ8,
    const int* __restrict__ ssrcS, const int* __restrict__ sdstS,
    const float* __restrict__ bs, const float* __restrict__ bg,
    float* __restrict__ acc)
{
    __shared__ int s_src[4][64];
    __shared__ int s_dst[4][64];
    const int t = threadIdx.x & 63;
    const int w = threadIdx.x >> 6;
    const size_t p0 = ((size_t)blockIdx.x * 4 + w) * 64;
    s_src[w][t] = ssrcS[p0 + t];
    s_dst[w][t] = sdstS[p0 + t];
    __syncthreads();

    const float2 bsv = *(const float2*)&bs[2 * t];
    const float2 bgv = *(const float2*)&bg[2 * t];
    const char* PQl = PQ8 + 8 * t;           // lane base into PQ
    char* accl = (char*)acc + 8 * t;         // lane base into acc
    const char* Cl = C8 + p0 * 512 + 8 * t;  // C row stride = 512 B

    int cur = s_src[w][0];
    u32x2 pv = *(const u32x2*)(PQl + cur);
    float psA = unp_lo(pv.x) + bsv.x, pgA = unp_hi(pv.x) + bgv.x;
    float psB = unp_lo(pv.y) + bsv.y, pgB = unp_hi(pv.y) + bgv.y;

    u32x2 c0 = __builtin_nontemporal_load((const u32x2*)(Cl + 0 * 512));
    u32x2 c1 = __builtin_nontemporal_load((const u32x2*)(Cl + 1 * 512));
    u32x2 c2 = __builtin_nontemporal_load((const u32x2*)(Cl + 2 * 512));
    u32x2 c3 = __builtin_nontemporal_load((const u32x2*)(Cl + 3 * 512));
    u32x2 q0 = *(const u32x2*)(PQl + s_dst[w][0]);
    u32x2 q1 = *(const u32x2*)(PQl + s_dst[w][1]);
    u32x2 q2 = *(const u32x2*)(PQl + s_dst[w][2]);
    u32x2 q3 = *(const u32x2*)(PQl + s_dst[w][3]);
    u32x2 r0 = pv, r1 = pv, r2 = pv, r3 = pv;
    if (s_src[w][1] != s_src[w][0]) r1 = *(const u32x2*)(PQl + s_src[w][1]);
    if (s_src[w][2] != s_src[w][1]) r2 = *(const u32x2*)(PQl + s_src[w][2]);
    if (s_src[w][3] != s_src[w][2]) r3 = *(const u32x2*)(PQl + s_src[w][3]);
    float accA = 0.f, accB = 0.f;

#define PROC_CORE(i, cc, qq, rr)                                           \
    {                                                                      \
        int src_ = s_src[w][(i)];                                          \
        if (src_ != cur) {                                                 \
            atomicAdd((float*)(accl + (cur >> 1)),     accA);              \
            atomicAdd((float*)(accl + (cur >> 1) + 4), accB);              \
            accA = 0.f; accB = 0.f; cur = src_;                            \
            psA = unp_lo(rr.x) + bsv.x; pgA = unp_hi(rr.x) + bgv.x;        \
            psB = unp_lo(rr.y) + bsv.y; pgB = unp_hi(rr.y) + bgv.y;        \
        }                                                                  \
        float sA = unp_lo(cc.x) + unp_lo(qq.x) + psA;                      \
        float gA = unp_hi(cc.x) + unp_hi(qq.x) + pgA;                      \
        float sB = unp_lo(cc.y) + unp_lo(qq.y) + psB;                      \
        float gB = unp_hi(cc.y) + unp_hi(qq.y) + pgB;                      \
        accA = fmaf(sigmoid_nb(sA), softplus_fast(gA), accA);              \
        accB = fmaf(sigmoid_nb(sB), softplus_fast(gB), accB);              \
    }

#define PROC(i, cc, qq, rr)                                                \
    PROC_CORE(i, cc, qq, rr)                                               \
    {                                                                      \
        int nx_ = (i) + 4;                                                 \
        cc = __builtin_nontemporal_load((const u32x2*)(Cl + nx_ * 512));   \
        qq = *(const u32x2*)(PQl + s_dst[w][nx_]);                         \
        if (s_src[w][nx_] != s_src[w][nx_ - 1])                            \
            rr = *(const u32x2*)(PQl + s_src[w][nx_]);                     \
    }

    for (int j = 0; j < 15; ++j) {
        int b = 4 * j;
        PROC(b + 0, c0, q0, r0)
        PROC(b + 1, c1, q1, r1)
        PROC(b + 2, c2, q2, r2)
        PROC(b + 3, c3, q3, r3)
    }
    PROC_CORE(60, c0, q0, r0)
    PROC_CORE(61, c1, q1, r1)
    PROC_CORE(62, c2, q2, r2)
    PROC_CORE(63, c3, q3, r3)

    atomicAdd((float*)(accl + (cur >> 1)),     accA);
    atomicAdd((float*)(accl + (cur >> 1) + 4), accB);
#undef PROC
#undef PROC_CORE
}

// ===== final softplus =====
__global__ void __launch_bounds__(256) act_k(float* __restrict__ acc)
{
    size_t i = ((size_t)blockIdx.x * 256 + threadIdx.x) * 4;
    float4 v = *(float4*)&acc[i];
    v.x = softplus_f(v.x);
    v.y = softplus_f(v.y);
    v.z = softplus_f(v.z);
    v.w = softplus_f(v.w);
    *(float4*)&acc[i] = v;
}

// ===== Tier B fallback (round-1, known good) =====
__global__ void __launch_bounds__(128) node_mm_f32(
    const float* __restrict__ x, const float* __restrict__ Ks,
    const float* __restrict__ Kg, float* __restrict__ PQ)
{
    __shared__ float xs[8][AD];
    const int t = threadIdx.x;
    const int row0 = blockIdx.x * 8;
#pragma unroll
    for (int r = 0; r < 8; ++r) xs[r][t] = x[(size_t)(row0 + r) * AD + t];
    __syncthreads();
    float aPs[8] = {}, aQs[8] = {}, aPg[8] = {}, aQg[8] = {};
    for (int k = 0; k < AD; ++k) {
        float ks_s = Ks[k * AD + t];
        float ks_d = Ks[(AD + k) * AD + t];
        float kg_s = Kg[k * AD + t];
        float kg_d = Kg[(AD + k) * AD + t];
#pragma unroll
        for (int r = 0; r < 8; ++r) {
            float xv = xs[r][k];
            aPs[r] = fmaf(xv, ks_s, aPs[r]);
            aQs[r] = fmaf(xv, ks_d, aQs[r]);
            aPg[r] = fmaf(xv, kg_s, aPg[r]);
            aQg[r] = fmaf(xv, kg_d, aQg[r]);
        }
    }
#pragma unroll
    for (int r = 0; r < 8; ++r) {
        float* o = PQ + (size_t)(row0 + r) * 512;
        *(float2*)&o[2 * t]       = make_float2(aPs[r], aPg[r]);
        *(float2*)&o[256 + 2 * t] = make_float2(aQs[r], aQg[r]);
    }
}

__global__ void __launch_bounds__(256) edge_fused(
    const float* __restrict__ ef, const float* __restrict__ Ks,
    const float* __restrict__ Kg, const float* __restrict__ PQ,
    const int* __restrict__ pidx, const float* __restrict__ bs,
    const float* __restrict__ bg, float* __restrict__ acc)
{
    __shared__ float KB[ED][2 * AD];
    __shared__ float es[64][ED];
    const int t = threadIdx.x;
    for (int i = t; i < ED * AD; i += 256) {
        int k = i >> 7, n = i & 127;
        KB[k][2 * n]     = Ks[(2 * AD + k) * AD + n];
        KB[k][2 * n + 1] = Kg[(2 * AD + k) * AD + n];
    }
    const size_t e0 = (size_t)blockIdx.x * 64;
    for (int i = t; i < 64 * ED; i += 256) ((float*)es)[i] = ef[e0 * ED + i];
    __syncthreads();
    const int le = t >> 7, n = t & 127;
    const float bsn = bs[n], bgn = bg[n];
    for (int base = le * 8; base < 64; base += 16) {
        float accS[8] = {}, accG[8] = {};
        for (int k4 = 0; k4 < ED / 4; ++k4) {
            float2 kv0 = *(const float2*)&KB[4 * k4 + 0][2 * n];
            float2 kv1 = *(const float2*)&KB[4 * k4 + 1][2 * n];
            float2 kv2 = *(const float2*)&KB[4 * k4 + 2][2 * n];
            float2 kv3 = *(const float2*)&KB[4 * k4 + 3][2 * n];
#pragma unroll
            for (int r = 0; r < 8; ++r) {
                float4 ev = *(const float4*)&es[base + r][4 * k4];
                accS[r] = fmaf(ev.x, kv0.x, accS[r]);
                accG[r] = fmaf(ev.x, kv0.y, accG[r]);
                accS[r] = fmaf(ev.y, kv1.x, accS[r]);
                accG[r] = fmaf(ev.y, kv1.y, accG[r]);
                accS[r] = fmaf(ev.z, kv2.x, accS[r]);
                accG[r] = fmaf(ev.z, kv2.y, accG[r]);
                accS[r] = fmaf(ev.w, kv3.x, accS[r]);
                accG[r] = fmaf(ev.w, kv3.y, accG[r]);
            }
        }
#pragma unroll
        for (int r = 0; r < 8; ++r) {
            size_t e = e0 + base + r;
            int src = pidx[2 * e], dst = pidx[2 * e + 1];
            float2 pv = *(const float2*)&PQ[(size_t)src * 512 + 2 * n];
            float2 qv = *(const float2*)&PQ[(size_t)dst * 512 + 256 + 2 * n];
            float s = accS[r] + pv.x + qv.x + bsn;
            float g = accG[r] + pv.y + qv.y + bgn;
            atomicAdd(&acc[(size_t)src * AD + n], sigmoid_fast(s) * softplus_f(g));
        }
    }
}

// ===== launch =====
extern "C" void kernel_launch(void* const* d_in, const int* in_sizes, int n_in,
                              void* d_out, int out_size, void* d_ws, size_t ws_size,
                              hipStream_t stream)
{
    const float* atom = (const float*)d_in[0];
    const float* ef   = (const float*)d_in[1];
    const float* Ks   = (const float*)d_in[3];
    const float* bs   = (const float*)d_in[4];
    const float* Kg   = (const float*)d_in[5];
    const float* bg   = (const float*)d_in[6];
    const int*   pidx = (const int*)d_in[7];

    float* acc = (float*)d_out;

    char* w = (char*)d_ws;
    const size_t PQ_B   = (size_t)NN * 256 * 4;   //  51.2 MB
    const size_t C_B    = (size_t)NE * 128 * 4;   // 409.6 MB
    const size_t CNT_B  = (size_t)NN * 4;
    const size_t IDX_B  = (size_t)NE * 4;
    const size_t PART_B = 256 * 4;
    unsigned* PQ32 = (unsigned*)w;  w += PQ_B;
    unsigned* C32  = (unsigned*)w;  w += C_B;
    unsigned* cnt  = (unsigned*)w;  w += CNT_B;
    unsigned* curp = (unsigned*)w;  w += CNT_B;
    int*      sid  = (int*)w;       w += IDX_B;
    int*      ssrc = (int*)w;       w += IDX_B;
    int*      sdst = (int*)w;       w += IDX_B;
    unsigned* part = (unsigned*)w;  w += PART_B;
    const size_t TOTAL_A = PQ_B + C_B + 2 * CNT_B + 3 * IDX_B + PART_B;

    if (ws_size >= TOTAL_A) {
        hipMemsetAsync(cnt, 0, CNT_B, stream);
        hist_k<<<NE / 256, 256, 0, stream>>>(pidx, cnt);
        scan1_k<<<NSCAN, 256, 0, stream>>>(cnt, curp, part);
        scan2_k<<<1, 256, 0, stream>>>(part);
        scan3_k<<<NSCAN, 256, 0, stream>>>(curp, part);
        scatter_k<<<NE / 256, 256, 0, stream>>>(pidx, curp, sid, ssrc, sdst);
        edge_c_mfma<<<1024, 512, 0, stream>>>(ef, Ks, Kg, sid, C32);

        for (int s = 0; s < NSTEPS; ++s) {
            node_mm_b16<<<NN / 16, 128, 0, stream>>>(atom, acc, Ks, Kg, PQ32,
                                                     s == 0 ? 0 : 1);
            edge_apply_sorted<<<NE / 256, 256, 0, stream>>>(
                (const char*)C32, (const char*)PQ32, ssrc, sdst, bs, bg, acc);
        }
        act_k<<<(NN * AD) / 1024, 256, 0, stream>>>(acc);
    } else {
        float* PQ = (float*)d_ws;
        hipMemcpyAsync(acc, atom, (size_t)NN * AD * sizeof(float),
                       hipMemcpyDeviceToDevice, stream);
        for (int s = 0; s < NSTEPS; ++s) {
            node_mm_f32<<<NN / 8, 128, 0, stream>>>(acc, Ks, Kg, PQ);
            edge_fused<<<NE / 64, 256, 0, stream>>>(ef, Ks, Kg, PQ, pidx, bs, bg, acc);
            act_k<<<(NN * AD) / 1024, 256, 0, stream>>>(acc);
        }
    }
}

// Round 8
// 819.444 us; speedup vs baseline: 1.2998x; 1.2137x over previous
//
#include <hip/hip_runtime.h>
#include <hip/hip_bf16.h>
#include <math.h>

// CrystalGraphConvolution — MI355X round 8
// vs r7: node_mm moved to MFMA (hi/lo bf16 split; B pre-packed once into a
// 256 KB global buffer; A tile in 32 KB LDS; P-pass then Q-pass to cap VGPR).
// edge_c grid 1024 -> 2048. Everything else = r7.

#define NN 50000
#define NE 800000
#define AD 128
#define ED 64
#define NSTEPS 3
#define NTILES (NE / 64)          // 12500
#define NSCAN  ((NN + 255) / 256) // 196
#define NROWB  ((NN + 63) / 64)   // 782 node row-tiles

typedef __attribute__((ext_vector_type(8))) __bf16 bf16x8;
typedef __attribute__((ext_vector_type(4))) float  f32x4;
typedef __attribute__((ext_vector_type(2))) unsigned u32x2;

__device__ __forceinline__ float sigmoid_nb(float x) {      // branch-free
    return __builtin_amdgcn_rcpf(1.f + __expf(-x));
}
__device__ __forceinline__ float softplus_fast(float x) {
    return fmaxf(x, 0.f) + __logf(1.f + __expf(-fabsf(x)));
}
__device__ __forceinline__ float softplus_f(float x) {      // precise (output path)
    return fmaxf(x, 0.f) + log1pf(__expf(-fabsf(x)));
}
__device__ __forceinline__ float sigmoid_fast(float x) {    // Tier B
    float e = __expf(-fabsf(x));
    float r = __builtin_amdgcn_rcpf(1.f + e);
    return (x >= 0.f) ? r : 1.f - r;
}
__device__ __forceinline__ unsigned short bf16_rne(float f) {
    unsigned u = __float_as_uint(f);
    unsigned r = u + 0x7fffu + ((u >> 16) & 1u);
    return (unsigned short)(r >> 16);
}
__device__ __forceinline__ unsigned pack_bf2(float s, float g) {
    return (unsigned)bf16_rne(s) | ((unsigned)bf16_rne(g) << 16);
}
__device__ __forceinline__ float unp_lo(unsigned v) { return __uint_as_float(v << 16); }
__device__ __forceinline__ float unp_hi(unsigned v) { return __uint_as_float(v & 0xffff0000u); }

// ===== one-time B pre-pack for node GEMM =====
// vector idx = ((((sel*2+m)*2+hl)*4+ki)*512) + col*4 + l4   (16384 x 16B = 256 KB)
// element j = K_m[sel*128 + ki*32 + l4*8 + j][col]  (hi or lo bf16 plane)
__global__ void __launch_bounds__(256) bn_prep(
    const float* __restrict__ Ks, const float* __restrict__ Kg,
    bf16x8* __restrict__ Bn)
{
    union U8 { short s[8]; bf16x8 v; };
    int idx = blockIdx.x * 256 + threadIdx.x;      // 64 blocks -> 16384
    int l4  = idx & 3;
    int col = (idx >> 2) & 127;
    int ki  = (idx >> 9) & 3;
    int hl  = (idx >> 11) & 1;
    int m   = (idx >> 12) & 1;
    int sel = (idx >> 13) & 1;
    const float* K = m ? Kg : Ks;
    U8 o;
#pragma unroll
    for (int j = 0; j < 8; ++j) {
        int k = sel * 128 + ki * 32 + l4 * 8 + j;
        float v = K[(size_t)k * AD + col];
        unsigned short h = bf16_rne(v);
        o.s[j] = (hl == 0) ? (short)h
                           : (short)bf16_rne(v - __uint_as_float((unsigned)h << 16));
    }
    Bn[idx] = o.v;
}

// ===== node projections via MFMA (hi/lo), + x maintenance =====
// mode 0: x = xin, acc = xin ; mode 1: x = softplus(acc), acc = x
__global__ void __launch_bounds__(512, 1) node_mm_mfma(
    const float* __restrict__ xin, float* __restrict__ acc,
    const bf16x8* __restrict__ Bn, unsigned* __restrict__ PQ32, int mode)
{
    __shared__ short As_h[64 * 128];
    __shared__ short As_l[64 * 128];
    const int t = threadIdx.x;
    const int w = t >> 6, lane = t & 63;
    const int l4 = lane >> 4;
    const int row0 = blockIdx.x * 64;

    // ---- stage A: 64 rows x 128 k, f32 -> hi/lo bf16, swizzled ----
#pragma unroll
    for (int ii = 0; ii < 4; ++ii) {
        int idx = t + 512 * ii;            // 2048 float4
        int row = idx >> 5, c4 = idx & 31;
        int node = row0 + row;
        f32x4 v = {};
        if (node < NN) {
            if (mode == 0) {
                v = *(const f32x4*)&xin[(size_t)node * AD + 4 * c4];
                *(f32x4*)&acc[(size_t)node * AD + 4 * c4] = v;
            } else {
                f32x4 a = *(const f32x4*)&acc[(size_t)node * AD + 4 * c4];
                v[0] = softplus_f(a[0]); v[1] = softplus_f(a[1]);
                v[2] = softplus_f(a[2]); v[3] = softplus_f(a[3]);
                *(f32x4*)&acc[(size_t)node * AD + 4 * c4] = v;
            }
        }
        unsigned short h0 = bf16_rne(v[0]), h1 = bf16_rne(v[1]),
                       h2 = bf16_rne(v[2]), h3 = bf16_rne(v[3]);
        unsigned short l0 = bf16_rne(v[0] - __uint_as_float((unsigned)h0 << 16));
        unsigned short l1 = bf16_rne(v[1] - __uint_as_float((unsigned)h1 << 16));
        unsigned short l2 = bf16_rne(v[2] - __uint_as_float((unsigned)h2 << 16));
        unsigned short l3 = bf16_rne(v[3] - __uint_as_float((unsigned)h3 << 16));
        int sidx = (row * 128 + c4 * 4) ^ ((row & 7) << 3);
        *(short4*)&As_h[sidx] = make_short4((short)h0, (short)h1, (short)h2, (short)h3);
        *(short4*)&As_l[sidx] = make_short4((short)l0, (short)l1, (short)l2, (short)l3);
    }
    __syncthreads();

    const int col = w * 16 + (lane & 15);
    // ---- two passes: sel=0 (P, k-top), sel=1 (Q, k-mid) ----
#pragma unroll
    for (int sel = 0; sel < 2; ++sel) {
        bf16x8 bS[4][2], bG[4][2];
#pragma unroll
        for (int ki = 0; ki < 4; ++ki) {
#pragma unroll
            for (int hl = 0; hl < 2; ++hl) {
                bS[ki][hl] = Bn[(((sel * 2 + 0) * 2 + hl) * 4 + ki) * 512 + col * 4 + l4];
                bG[ki][hl] = Bn[(((sel * 2 + 1) * 2 + hl) * 4 + ki) * 512 + col * 4 + l4];
            }
        }
        f32x4 aS[4] = {}, aG[4] = {};
#pragma unroll
        for (int mt = 0; mt < 4; ++mt) {
            int row = mt * 16 + (lane & 15);
#pragma unroll
            for (int ki = 0; ki < 4; ++ki) {
                int idx = (row * 128 + ki * 32 + l4 * 8) ^ ((row & 7) << 3);
                bf16x8 ah = *(const bf16x8*)&As_h[idx];
                bf16x8 al = *(const bf16x8*)&As_l[idx];
                aS[mt] = __builtin_amdgcn_mfma_f32_16x16x32_bf16(ah, bS[ki][0], aS[mt], 0, 0, 0);
                aS[mt] = __builtin_amdgcn_mfma_f32_16x16x32_bf16(al, bS[ki][0], aS[mt], 0, 0, 0);
                aS[mt] = __builtin_amdgcn_mfma_f32_16x16x32_bf16(ah, bS[ki][1], aS[mt], 0, 0, 0);
                aG[mt] = __builtin_amdgcn_mfma_f32_16x16x32_bf16(ah, bG[ki][0], aG[mt], 0, 0, 0);
                aG[mt] = __builtin_amdgcn_mfma_f32_16x16x32_bf16(al, bG[ki][0], aG[mt], 0, 0, 0);
                aG[mt] = __builtin_amdgcn_mfma_f32_16x16x32_bf16(ah, bG[ki][1], aG[mt], 0, 0, 0);
            }
        }
#pragma unroll
        for (int mt = 0; mt < 4; ++mt) {
#pragma unroll
            for (int reg = 0; reg < 4; ++reg) {
                int node = row0 + mt * 16 + l4 * 4 + reg;
                if (node < NN)
                    PQ32[(size_t)node * 256 + sel * 128 + col] =
                        pack_bf2(aS[mt][reg], aG[mt][reg]);
            }
        }
    }
}

// ===== sort machinery =====
__global__ void __launch_bounds__(256) hist_k(const int* __restrict__ pidx,
                                              unsigned* __restrict__ cnt)
{
    int e = blockIdx.x * 256 + threadIdx.x;
    atomicAdd(&cnt[pidx[2 * e]], 1u);
}

__global__ void __launch_bounds__(256) scan1_k(const unsigned* __restrict__ cnt,
                                               unsigned* __restrict__ cur,
                                               unsigned* __restrict__ part)
{
    __shared__ unsigned tmp[256];
    const int t = threadIdx.x;
    const int bin = blockIdx.x * 256 + t;
    unsigned v = (bin < NN) ? cnt[bin] : 0u;
    tmp[t] = v;
    __syncthreads();
    for (int off = 1; off < 256; off <<= 1) {
        unsigned a = (t >= off) ? tmp[t - off] : 0u;
        __syncthreads();
        tmp[t] += a;
        __syncthreads();
    }
    if (bin < NN) cur[bin] = tmp[t] - v;
    if (t == 255) part[blockIdx.x] = tmp[255];
}

__global__ void __launch_bounds__(256) scan2_k(unsigned* __restrict__ part)
{
    __shared__ unsigned tmp[256];
    const int t = threadIdx.x;
    unsigned v = (t < NSCAN) ? part[t] : 0u;
    tmp[t] = v;
    __syncthreads();
    for (int off = 1; off < 256; off <<= 1) {
        unsigned a = (t >= off) ? tmp[t - off] : 0u;
        __syncthreads();
        tmp[t] += a;
        __syncthreads();
    }
    if (t < NSCAN) part[t] = tmp[t] - v;
}

__global__ void __launch_bounds__(256) scan3_k(unsigned* __restrict__ cur,
                                               const unsigned* __restrict__ part)
{
    const int bin = blockIdx.x * 256 + threadIdx.x;
    if (bin < NN) cur[bin] += part[blockIdx.x];
}

// scaled offsets: ssrc = src*1024 (P byte off), sdst = dst*1024+512 (Q byte off)
__global__ void __launch_bounds__(256) scatter_k(
    const int* __restrict__ pidx, unsigned* __restrict__ cur,
    int* __restrict__ sid, int* __restrict__ ssrc, int* __restrict__ sdst)
{
    int e = blockIdx.x * 256 + threadIdx.x;
    int s = pidx[2 * e], d = pidx[2 * e + 1];
    unsigned pos = atomicAdd(&cur[s], 1u);
    sid[pos] = e;
    ssrc[pos] = s << 10;
    sdst[pos] = (d << 10) + 512;
}

// ===== C = ef @ K_bot via MFMA (hi/lo split), gather-read / linear-write =====
__global__ void __launch_bounds__(512) edge_c_mfma(
    const float* __restrict__ ef, const float* __restrict__ Ks,
    const float* __restrict__ Kg, const int* __restrict__ sid,
    unsigned* __restrict__ C32)
{
    __shared__ short As_h[64 * 64];
    __shared__ short As_l[64 * 64];
    const int t = threadIdx.x;
    const int w = t >> 6, lane = t & 63;

    union U8 { short s[8]; bf16x8 v; };
    bf16x8 bS[2][2], bG[2][2];   // [ki][hi/lo]
    {
        const int col = w * 16 + (lane & 15);
#pragma unroll
        for (int ki = 0; ki < 2; ++ki) {
            U8 sh_, sl_, gh_, gl_;
            const int kbase = 2 * AD + ki * 32 + (lane >> 4) * 8;
#pragma unroll
            for (int j = 0; j < 8; ++j) {
                float vs = Ks[(size_t)(kbase + j) * AD + col];
                float vg = Kg[(size_t)(kbase + j) * AD + col];
                unsigned short h = bf16_rne(vs);
                sh_.s[j] = (short)h;
                sl_.s[j] = (short)bf16_rne(vs - __uint_as_float((unsigned)h << 16));
                h = bf16_rne(vg);
                gh_.s[j] = (short)h;
                gl_.s[j] = (short)bf16_rne(vg - __uint_as_float((unsigned)h << 16));
            }
            bS[ki][0] = sh_.v; bS[ki][1] = sl_.v;
            bG[ki][0] = gh_.v; bG[ki][1] = gl_.v;
        }
    }

    const int srow = t >> 4, sc4 = t & 15;
    f32x4 pf0, pf1;
    {
        int ea = sid[(size_t)blockIdx.x * 64 + srow];
        int eb = sid[(size_t)blockIdx.x * 64 + srow + 32];
        pf0 = __builtin_nontemporal_load((const f32x4*)&ef[(size_t)ea * 64 + 4 * sc4]);
        pf1 = __builtin_nontemporal_load((const f32x4*)&ef[(size_t)eb * 64 + 4 * sc4]);
    }

    for (int tile = blockIdx.x; tile < NTILES; tile += gridDim.x) {
        __syncthreads();
        {
            f32x4 v[2] = {pf0, pf1};
#pragma unroll
            for (int ii = 0; ii < 2; ++ii) {
                int row = srow + 32 * ii;
                float a0 = v[ii][0], a1 = v[ii][1], a2 = v[ii][2], a3 = v[ii][3];
                unsigned short h0 = bf16_rne(a0), h1 = bf16_rne(a1),
                               h2 = bf16_rne(a2), h3 = bf16_rne(a3);
                unsigned short l0 = bf16_rne(a0 - __uint_as_float((unsigned)h0 << 16));
                unsigned short l1 = bf16_rne(a1 - __uint_as_float((unsigned)h1 << 16));
                unsigned short l2 = bf16_rne(a2 - __uint_as_float((unsigned)h2 << 16));
                unsigned short l3 = bf16_rne(a3 - __uint_as_float((unsigned)h3 << 16));
                int sidx = (row * 64 + sc4 * 4) ^ ((row & 7) << 3);
                *(short4*)&As_h[sidx] = make_short4((short)h0, (short)h1, (short)h2, (short)h3);
                *(short4*)&As_l[sidx] = make_short4((short)l0, (short)l1, (short)l2, (short)l3);
            }
        }
        {
            int nxt = tile + gridDim.x;
            if (nxt < NTILES) {
                int ea = sid[(size_t)nxt * 64 + srow];
                int eb = sid[(size_t)nxt * 64 + srow + 32];
                pf0 = __builtin_nontemporal_load((const f32x4*)&ef[(size_t)ea * 64 + 4 * sc4]);
                pf1 = __builtin_nontemporal_load((const f32x4*)&ef[(size_t)eb * 64 + 4 * sc4]);
            }
        }
        __syncthreads();

        f32x4 accS[4] = {}, accG[4] = {};
#pragma unroll
        for (int mt = 0; mt < 4; ++mt) {
#pragma unroll
            for (int ki = 0; ki < 2; ++ki) {
                int row = mt * 16 + (lane & 15);
                int idx = (row * 64 + ki * 32 + (lane >> 4) * 8) ^ ((row & 7) << 3);
                bf16x8 ah = *(const bf16x8*)&As_h[idx];
                bf16x8 al = *(const bf16x8*)&As_l[idx];
                accS[mt] = __builtin_amdgcn_mfma_f32_16x16x32_bf16(ah, bS[ki][0], accS[mt], 0, 0, 0);
                accS[mt] = __builtin_amdgcn_mfma_f32_16x16x32_bf16(al, bS[ki][0], accS[mt], 0, 0, 0);
                accS[mt] = __builtin_amdgcn_mfma_f32_16x16x32_bf16(ah, bS[ki][1], accS[mt], 0, 0, 0);
                accG[mt] = __builtin_amdgcn_mfma_f32_16x16x32_bf16(ah, bG[ki][0], accG[mt], 0, 0, 0);
                accG[mt] = __builtin_amdgcn_mfma_f32_16x16x32_bf16(al, bG[ki][0], accG[mt], 0, 0, 0);
                accG[mt] = __builtin_amdgcn_mfma_f32_16x16x32_bf16(ah, bG[ki][1], accG[mt], 0, 0, 0);
            }
        }
        const size_t p0 = (size_t)tile * 64;
#pragma unroll
        for (int mt = 0; mt < 4; ++mt) {
#pragma unroll
            for (int reg = 0; reg < 4; ++reg) {
                int row = mt * 16 + (lane >> 4) * 4 + reg;
                unsigned val = pack_bf2(accS[mt][reg], accG[mt][reg]);
                __builtin_nontemporal_store(val,
                    &C32[(p0 + row) * 128 + w * 16 + (lane & 15)]);
            }
        }
    }
}

// ===== sorted apply v3: byte-offset addressing, branch-free sigmoid =====
__global__ void __launch_bounds__(256) edge_apply_sorted(
    const char* __restrict__ C8, const char* __restrict__ PQ8,
    const int* __restrict__ ssrcS, const int* __restrict__ sdstS,
    const float* __restrict__ bs, const float* __restrict__ bg,
    float* __restrict__ acc)
{
    __shared__ int s_src[4][64];
    __shared__ int s_dst[4][64];
    const int t = threadIdx.x & 63;
    const int w = threadIdx.x >> 6;
    const size_t p0 = ((size_t)blockIdx.x * 4 + w) * 64;
    s_src[w][t] = ssrcS[p0 + t];
    s_dst[w][t] = sdstS[p0 + t];
    __syncthreads();

    const float2 bsv = *(const float2*)&bs[2 * t];
    const float2 bgv = *(const float2*)&bg[2 * t];
    const char* PQl = PQ8 + 8 * t;
    char* accl = (char*)acc + 8 * t;
    const char* Cl = C8 + p0 * 512 + 8 * t;

    int cur = s_src[w][0];
    u32x2 pv = *(const u32x2*)(PQl + cur);
    float psA = unp_lo(pv.x) + bsv.x, pgA = unp_hi(pv.x) + bgv.x;
    float psB = unp_lo(pv.y) + bsv.y, pgB = unp_hi(pv.y) + bgv.y;

    u32x2 c0 = __builtin_nontemporal_load((const u32x2*)(Cl + 0 * 512));
    u32x2 c1 = __builtin_nontemporal_load((const u32x2*)(Cl + 1 * 512));
    u32x2 c2 = __builtin_nontemporal_load((const u32x2*)(Cl + 2 * 512));
    u32x2 c3 = __builtin_nontemporal_load((const u32x2*)(Cl + 3 * 512));
    u32x2 q0 = *(const u32x2*)(PQl + s_dst[w][0]);
    u32x2 q1 = *(const u32x2*)(PQl + s_dst[w][1]);
    u32x2 q2 = *(const u32x2*)(PQl + s_dst[w][2]);
    u32x2 q3 = *(const u32x2*)(PQl + s_dst[w][3]);
    u32x2 r0 = pv, r1 = pv, r2 = pv, r3 = pv;
    if (s_src[w][1] != s_src[w][0]) r1 = *(const u32x2*)(PQl + s_src[w][1]);
    if (s_src[w][2] != s_src[w][1]) r2 = *(const u32x2*)(PQl + s_src[w][2]);
    if (s_src[w][3] != s_src[w][2]) r3 = *(const u32x2*)(PQl + s_src[w][3]);
    float accA = 0.f, accB = 0.f;

#define PROC_CORE(i, cc, qq, rr)                                           \
    {                                                                      \
        int src_ = s_src[w][(i)];                                          \
        if (src_ != cur) {                                                 \
            atomicAdd((float*)(accl + (cur >> 1)),     accA);              \
            atomicAdd((float*)(accl + (cur >> 1) + 4), accB);              \
            accA = 0.f; accB = 0.f; cur = src_;                            \
            psA = unp_lo(rr.x) + bsv.x; pgA = unp_hi(rr.x) + bgv.x;        \
            psB = unp_lo(rr.y) + bsv.y; pgB = unp_hi(rr.y) + bgv.y;        \
        }                                                                  \
        float sA = unp_lo(cc.x) + unp_lo(qq.x) + psA;                      \
        float gA = unp_hi(cc.x) + unp_hi(qq.x) + pgA;                      \
        float sB = unp_lo(cc.y) + unp_lo(qq.y) + psB;                      \
        float gB = unp_hi(cc.y) + unp_hi(qq.y) + pgB;                      \
        accA = fmaf(sigmoid_nb(sA), softplus_fast(gA), accA);              \
        accB = fmaf(sigmoid_nb(sB), softplus_fast(gB), accB);              \
    }

#define PROC(i, cc, qq, rr)                                                \
    PROC_CORE(i, cc, qq, rr)                                               \
    {                                                                      \
        int nx_ = (i) + 4;                                                 \
        cc = __builtin_nontemporal_load((const u32x2*)(Cl + nx_ * 512));   \
        qq = *(const u32x2*)(PQl + s_dst[w][nx_]);                         \
        if (s_src[w][nx_] != s_src[w][nx_ - 1])                            \
            rr = *(const u32x2*)(PQl + s_src[w][nx_]);                     \
    }

    for (int j = 0; j < 15; ++j) {
        int b = 4 * j;
        PROC(b + 0, c0, q0, r0)
        PROC(b + 1, c1, q1, r1)
        PROC(b + 2, c2, q2, r2)
        PROC(b + 3, c3, q3, r3)
    }
    PROC_CORE(60, c0, q0, r0)
    PROC_CORE(61, c1, q1, r1)
    PROC_CORE(62, c2, q2, r2)
    PROC_CORE(63, c3, q3, r3)

    atomicAdd((float*)(accl + (cur >> 1)),     accA);
    atomicAdd((float*)(accl + (cur >> 1) + 4), accB);
#undef PROC
#undef PROC_CORE
}

// ===== final softplus =====
__global__ void __launch_bounds__(256) act_k(float* __restrict__ acc)
{
    size_t i = ((size_t)blockIdx.x * 256 + threadIdx.x) * 4;
    float4 v = *(float4*)&acc[i];
    v.x = softplus_f(v.x);
    v.y = softplus_f(v.y);
    v.z = softplus_f(v.z);
    v.w = softplus_f(v.w);
    *(float4*)&acc[i] = v;
}

// ===== Tier B fallback (round-1, known good) =====
__global__ void __launch_bounds__(128) node_mm_f32(
    const float* __restrict__ x, const float* __restrict__ Ks,
    const float* __restrict__ Kg, float* __restrict__ PQ)
{
    __shared__ float xs[8][AD];
    const int t = threadIdx.x;
    const int row0 = blockIdx.x * 8;
#pragma unroll
    for (int r = 0; r < 8; ++r) xs[r][t] = x[(size_t)(row0 + r) * AD + t];
    __syncthreads();
    float aPs[8] = {}, aQs[8] = {}, aPg[8] = {}, aQg[8] = {};
    for (int k = 0; k < AD; ++k) {
        float ks_s = Ks[k * AD + t];
        float ks_d = Ks[(AD + k) * AD + t];
        float kg_s = Kg[k * AD + t];
        float kg_d = Kg[(AD + k) * AD + t];
#pragma unroll
        for (int r = 0; r < 8; ++r) {
            float xv = xs[r][k];
            aPs[r] = fmaf(xv, ks_s, aPs[r]);
            aQs[r] = fmaf(xv, ks_d, aQs[r]);
            aPg[r] = fmaf(xv, kg_s, aPg[r]);
            aQg[r] = fmaf(xv, kg_d, aQg[r]);
        }
    }
#pragma unroll
    for (int r = 0; r < 8; ++r) {
        float* o = PQ + (size_t)(row0 + r) * 512;
        *(float2*)&o[2 * t]       = make_float2(aPs[r], aPg[r]);
        *(float2*)&o[256 + 2 * t] = make_float2(aQs[r], aQg[r]);
    }
}

__global__ void __launch_bounds__(256) edge_fused(
    const float* __restrict__ ef, const float* __restrict__ Ks,
    const float* __restrict__ Kg, const float* __restrict__ PQ,
    const int* __restrict__ pidx, const float* __restrict__ bs,
    const float* __restrict__ bg, float* __restrict__ acc)
{
    __shared__ float KB[ED][2 * AD];
    __shared__ float es[64][ED];
    const int t = threadIdx.x;
    for (int i = t; i < ED * AD; i += 256) {
        int k = i >> 7, n = i & 127;
        KB[k][2 * n]     = Ks[(2 * AD + k) * AD + n];
        KB[k][2 * n + 1] = Kg[(2 * AD + k) * AD + n];
    }
    const size_t e0 = (size_t)blockIdx.x * 64;
    for (int i = t; i < 64 * ED; i += 256) ((float*)es)[i] = ef[e0 * ED + i];
    __syncthreads();
    const int le = t >> 7, n = t & 127;
    const float bsn = bs[n], bgn = bg[n];
    for (int base = le * 8; base < 64; base += 16) {
        float accS[8] = {}, accG[8] = {};
        for (int k4 = 0; k4 < ED / 4; ++k4) {
            float2 kv0 = *(const float2*)&KB[4 * k4 + 0][2 * n];
            float2 kv1 = *(const float2*)&KB[4 * k4 + 1][2 * n];
            float2 kv2 = *(const float2*)&KB[4 * k4 + 2][2 * n];
            float2 kv3 = *(const float2*)&KB[4 * k4 + 3][2 * n];
#pragma unroll
            for (int r = 0; r < 8; ++r) {
                float4 ev = *(const float4*)&es[base + r][4 * k4];
                accS[r] = fmaf(ev.x, kv0.x, accS[r]);
                accG[r] = fmaf(ev.x, kv0.y, accG[r]);
                accS[r] = fmaf(ev.y, kv1.x, accS[r]);
                accG[r] = fmaf(ev.y, kv1.y, accG[r]);
                accS[r] = fmaf(ev.z, kv2.x, accS[r]);
                accG[r] = fmaf(ev.z, kv2.y, accG[r]);
                accS[r] = fmaf(ev.w, kv3.x, accS[r]);
                accG[r] = fmaf(ev.w, kv3.y, accG[r]);
            }
        }
#pragma unroll
        for (int r = 0; r < 8; ++r) {
            size_t e = e0 + base + r;
            int src = pidx[2 * e], dst = pidx[2 * e + 1];
            float2 pv = *(const float2*)&PQ[(size_t)src * 512 + 2 * n];
            float2 qv = *(const float2*)&PQ[(size_t)dst * 512 + 256 + 2 * n];
            float s = accS[r] + pv.x + qv.x + bsn;
            float g = accG[r] + pv.y + qv.y + bgn;
            atomicAdd(&acc[(size_t)src * AD + n], sigmoid_fast(s) * softplus_f(g));
        }
    }
}

// ===== launch =====
extern "C" void kernel_launch(void* const* d_in, const int* in_sizes, int n_in,
                              void* d_out, int out_size, void* d_ws, size_t ws_size,
                              hipStream_t stream)
{
    const float* atom = (const float*)d_in[0];
    const float* ef   = (const float*)d_in[1];
    const float* Ks   = (const float*)d_in[3];
    const float* bs   = (const float*)d_in[4];
    const float* Kg   = (const float*)d_in[5];
    const float* bg   = (const float*)d_in[6];
    const int*   pidx = (const int*)d_in[7];

    float* acc = (float*)d_out;

    char* w = (char*)d_ws;
    const size_t PQ_B   = (size_t)NN * 256 * 4;   //  51.2 MB
    const size_t C_B    = (size_t)NE * 128 * 4;   // 409.6 MB
    const size_t BN_B   = 16384 * 16;             // 256 KB
    const size_t CNT_B  = (size_t)NN * 4;
    const size_t IDX_B  = (size_t)NE * 4;
    const size_t PART_B = 256 * 4;
    unsigned* PQ32 = (unsigned*)w;  w += PQ_B;
    unsigned* C32  = (unsigned*)w;  w += C_B;
    bf16x8*   Bn   = (bf16x8*)w;    w += BN_B;
    unsigned* cnt  = (unsigned*)w;  w += CNT_B;
    unsigned* curp = (unsigned*)w;  w += CNT_B;
    int*      sid  = (int*)w;       w += IDX_B;
    int*      ssrc = (int*)w;       w += IDX_B;
    int*      sdst = (int*)w;       w += IDX_B;
    unsigned* part = (unsigned*)w;  w += PART_B;
    const size_t TOTAL_A = PQ_B + C_B + BN_B + 2 * CNT_B + 3 * IDX_B + PART_B;

    if (ws_size >= TOTAL_A) {
        hipMemsetAsync(cnt, 0, CNT_B, stream);
        bn_prep<<<64, 256, 0, stream>>>(Ks, Kg, Bn);
        hist_k<<<NE / 256, 256, 0, stream>>>(pidx, cnt);
        scan1_k<<<NSCAN, 256, 0, stream>>>(cnt, curp, part);
        scan2_k<<<1, 256, 0, stream>>>(part);
        scan3_k<<<NSCAN, 256, 0, stream>>>(curp, part);
        scatter_k<<<NE / 256, 256, 0, stream>>>(pidx, curp, sid, ssrc, sdst);
        edge_c_mfma<<<2048, 512, 0, stream>>>(ef, Ks, Kg, sid, C32);

        for (int s = 0; s < NSTEPS; ++s) {
            node_mm_mfma<<<NROWB, 512, 0, stream>>>(atom, acc, Bn, PQ32,
                                                    s == 0 ? 0 : 1);
            edge_apply_sorted<<<NE / 256, 256, 0, stream>>>(
                (const char*)C32, (const char*)PQ32, ssrc, sdst, bs, bg, acc);
        }
        act_k<<<(NN * AD) / 1024, 256, 0, stream>>>(acc);
    } else {
        float* PQ = (float*)d_ws;
        hipMemcpyAsync(acc, atom, (size_t)NN * AD * sizeof(float),
                       hipMemcpyDeviceToDevice, stream);
        for (int s = 0; s < NSTEPS; ++s) {
            node_mm_f32<<<NN / 8, 128, 0, stream>>>(acc, Ks, Kg, PQ);
            edge_fused<<<NE / 64, 256, 0, stream>>>(ef, Ks, Kg, PQ, pidx, bs, bg, acc);
            act_k<<<(NN * AD) / 1024, 256, 0, stream>>>(acc);
        }
    }
}

// Round 9
// 805.854 us; speedup vs baseline: 1.3217x; 1.0169x over previous
//
#include <hip/hip_runtime.h>
#include <hip/hip_bf16.h>
#include <math.h>

// CrystalGraphConvolution — MI355X round 9
// vs r8: apply v4 — log2-domain (C/P/Q/bias pre-scaled by log2e at pack time;
// raw v_exp/v_log via inline asm with input modifiers; ln2 folded into run
// flush), readlane-scalarized run logic (SGPR cmp + s_cbranch, zero LDS).
// edge_c/node_mm epilogues scale packs by L2E. Everything else = r8.

#define NN 50000
#define NE 800000
#define AD 128
#define ED 64
#define NSTEPS 3
#define NTILES (NE / 64)          // 12500
#define NSCAN  ((NN + 255) / 256) // 196
#define NROWB  ((NN + 63) / 64)   // 782

#define L2E 1.4426950408889634f
#define LN2 0.6931471805599453f

typedef __attribute__((ext_vector_type(8))) __bf16 bf16x8;
typedef __attribute__((ext_vector_type(4))) float  f32x4;
typedef __attribute__((ext_vector_type(2))) unsigned u32x2;

__device__ __forceinline__ float softplus_f(float x) {      // precise (output path)
    return fmaxf(x, 0.f) + log1pf(__expf(-fabsf(x)));
}
__device__ __forceinline__ float sigmoid_fast(float x) {    // Tier B
    float e = __expf(-fabsf(x));
    float r = __builtin_amdgcn_rcpf(1.f + e);
    return (x >= 0.f) ? r : 1.f - r;
}
__device__ __forceinline__ unsigned short bf16_rne(float f) {
    unsigned u = __float_as_uint(f);
    unsigned r = u + 0x7fffu + ((u >> 16) & 1u);
    return (unsigned short)(r >> 16);
}
__device__ __forceinline__ unsigned pack_bf2(float s, float g) {
    return (unsigned)bf16_rne(s) | ((unsigned)bf16_rne(g) << 16);
}
__device__ __forceinline__ float unp_lo(unsigned v) { return __uint_as_float(v << 16); }
__device__ __forceinline__ float unp_hi(unsigned v) { return __uint_as_float(v & 0xffff0000u); }

// raw transcendental helpers (v_exp_f32 = 2^x, v_log_f32 = log2)
__device__ __forceinline__ float nexp2_f(float x) {         // 2^(-x)
    float r; asm("v_exp_f32 %0, -%1" : "=v"(r) : "v"(x)); return r;
}
__device__ __forceinline__ float nexp2_abs_f(float x) {     // 2^(-|x|)
    float r; asm("v_exp_f32 %0, -abs(%1)" : "=v"(r) : "v"(x)); return r;
}
__device__ __forceinline__ float log2_f(float x) {
    float r; asm("v_log_f32 %0, %1" : "=v"(r) : "v"(x)); return r;
}

// ===== one-time B pre-pack for node GEMM =====
__global__ void __launch_bounds__(256) bn_prep(
    const float* __restrict__ Ks, const float* __restrict__ Kg,
    bf16x8* __restrict__ Bn)
{
    union U8 { short s[8]; bf16x8 v; };
    int idx = blockIdx.x * 256 + threadIdx.x;      // 64 blocks -> 16384
    int l4  = idx & 3;
    int col = (idx >> 2) & 127;
    int ki  = (idx >> 9) & 3;
    int hl  = (idx >> 11) & 1;
    int m   = (idx >> 12) & 1;
    int sel = (idx >> 13) & 1;
    const float* K = m ? Kg : Ks;
    U8 o;
#pragma unroll
    for (int j = 0; j < 8; ++j) {
        int k = sel * 128 + ki * 32 + l4 * 8 + j;
        float v = K[(size_t)k * AD + col];
        unsigned short h = bf16_rne(v);
        o.s[j] = (hl == 0) ? (short)h
                           : (short)bf16_rne(v - __uint_as_float((unsigned)h << 16));
    }
    Bn[idx] = o.v;
}

// ===== node projections via MFMA (hi/lo), + x maintenance; outputs xL2E-scaled =====
__global__ void __launch_bounds__(512, 1) node_mm_mfma(
    const float* __restrict__ xin, float* __restrict__ acc,
    const bf16x8* __restrict__ Bn, unsigned* __restrict__ PQ32, int mode)
{
    __shared__ short As_h[64 * 128];
    __shared__ short As_l[64 * 128];
    const int t = threadIdx.x;
    const int w = t >> 6, lane = t & 63;
    const int l4 = lane >> 4;
    const int row0 = blockIdx.x * 64;

#pragma unroll
    for (int ii = 0; ii < 4; ++ii) {
        int idx = t + 512 * ii;
        int row = idx >> 5, c4 = idx & 31;
        int node = row0 + row;
        f32x4 v = {};
        if (node < NN) {
            if (mode == 0) {
                v = *(const f32x4*)&xin[(size_t)node * AD + 4 * c4];
                *(f32x4*)&acc[(size_t)node * AD + 4 * c4] = v;
            } else {
                f32x4 a = *(const f32x4*)&acc[(size_t)node * AD + 4 * c4];
                v[0] = softplus_f(a[0]); v[1] = softplus_f(a[1]);
                v[2] = softplus_f(a[2]); v[3] = softplus_f(a[3]);
                *(f32x4*)&acc[(size_t)node * AD + 4 * c4] = v;
            }
        }
        unsigned short h0 = bf16_rne(v[0]), h1 = bf16_rne(v[1]),
                       h2 = bf16_rne(v[2]), h3 = bf16_rne(v[3]);
        unsigned short l0 = bf16_rne(v[0] - __uint_as_float((unsigned)h0 << 16));
        unsigned short l1 = bf16_rne(v[1] - __uint_as_float((unsigned)h1 << 16));
        unsigned short l2 = bf16_rne(v[2] - __uint_as_float((unsigned)h2 << 16));
        unsigned short l3 = bf16_rne(v[3] - __uint_as_float((unsigned)h3 << 16));
        int sidx = (row * 128 + c4 * 4) ^ ((row & 7) << 3);
        *(short4*)&As_h[sidx] = make_short4((short)h0, (short)h1, (short)h2, (short)h3);
        *(short4*)&As_l[sidx] = make_short4((short)l0, (short)l1, (short)l2, (short)l3);
    }
    __syncthreads();

    const int col = w * 16 + (lane & 15);
#pragma unroll
    for (int sel = 0; sel < 2; ++sel) {
        bf16x8 bS[4][2], bG[4][2];
#pragma unroll
        for (int ki = 0; ki < 4; ++ki) {
#pragma unroll
            for (int hl = 0; hl < 2; ++hl) {
                bS[ki][hl] = Bn[(((sel * 2 + 0) * 2 + hl) * 4 + ki) * 512 + col * 4 + l4];
                bG[ki][hl] = Bn[(((sel * 2 + 1) * 2 + hl) * 4 + ki) * 512 + col * 4 + l4];
            }
        }
        f32x4 aS[4] = {}, aG[4] = {};
#pragma unroll
        for (int mt = 0; mt < 4; ++mt) {
            int row = mt * 16 + (lane & 15);
#pragma unroll
            for (int ki = 0; ki < 4; ++ki) {
                int idx = (row * 128 + ki * 32 + l4 * 8) ^ ((row & 7) << 3);
                bf16x8 ah = *(const bf16x8*)&As_h[idx];
                bf16x8 al = *(const bf16x8*)&As_l[idx];
                aS[mt] = __builtin_amdgcn_mfma_f32_16x16x32_bf16(ah, bS[ki][0], aS[mt], 0, 0, 0);
                aS[mt] = __builtin_amdgcn_mfma_f32_16x16x32_bf16(al, bS[ki][0], aS[mt], 0, 0, 0);
                aS[mt] = __builtin_amdgcn_mfma_f32_16x16x32_bf16(ah, bS[ki][1], aS[mt], 0, 0, 0);
                aG[mt] = __builtin_amdgcn_mfma_f32_16x16x32_bf16(ah, bG[ki][0], aG[mt], 0, 0, 0);
                aG[mt] = __builtin_amdgcn_mfma_f32_16x16x32_bf16(al, bG[ki][0], aG[mt], 0, 0, 0);
                aG[mt] = __builtin_amdgcn_mfma_f32_16x16x32_bf16(ah, bG[ki][1], aG[mt], 0, 0, 0);
            }
        }
#pragma unroll
        for (int mt = 0; mt < 4; ++mt) {
#pragma unroll
            for (int reg = 0; reg < 4; ++reg) {
                int node = row0 + mt * 16 + l4 * 4 + reg;
                if (node < NN)
                    PQ32[(size_t)node * 256 + sel * 128 + col] =
                        pack_bf2(aS[mt][reg] * L2E, aG[mt][reg] * L2E);
            }
        }
    }
}

// ===== sort machinery =====
__global__ void __launch_bounds__(256) hist_k(const int* __restrict__ pidx,
                                              unsigned* __restrict__ cnt)
{
    int e = blockIdx.x * 256 + threadIdx.x;
    atomicAdd(&cnt[pidx[2 * e]], 1u);
}

__global__ void __launch_bounds__(256) scan1_k(const unsigned* __restrict__ cnt,
                                               unsigned* __restrict__ cur,
                                               unsigned* __restrict__ part)
{
    __shared__ unsigned tmp[256];
    const int t = threadIdx.x;
    const int bin = blockIdx.x * 256 + t;
    unsigned v = (bin < NN) ? cnt[bin] : 0u;
    tmp[t] = v;
    __syncthreads();
    for (int off = 1; off < 256; off <<= 1) {
        unsigned a = (t >= off) ? tmp[t - off] : 0u;
        __syncthreads();
        tmp[t] += a;
        __syncthreads();
    }
    if (bin < NN) cur[bin] = tmp[t] - v;
    if (t == 255) part[blockIdx.x] = tmp[255];
}

__global__ void __launch_bounds__(256) scan2_k(unsigned* __restrict__ part)
{
    __shared__ unsigned tmp[256];
    const int t = threadIdx.x;
    unsigned v = (t < NSCAN) ? part[t] : 0u;
    tmp[t] = v;
    __syncthreads();
    for (int off = 1; off < 256; off <<= 1) {
        unsigned a = (t >= off) ? tmp[t - off] : 0u;
        __syncthreads();
        tmp[t] += a;
        __syncthreads();
    }
    if (t < NSCAN) part[t] = tmp[t] - v;
}

__global__ void __launch_bounds__(256) scan3_k(unsigned* __restrict__ cur,
                                               const unsigned* __restrict__ part)
{
    const int bin = blockIdx.x * 256 + threadIdx.x;
    if (bin < NN) cur[bin] += part[blockIdx.x];
}

// scaled offsets: ssrc = src*1024 (P byte off), sdst = dst*1024+512 (Q byte off)
__global__ void __launch_bounds__(256) scatter_k(
    const int* __restrict__ pidx, unsigned* __restrict__ cur,
    int* __restrict__ sid, int* __restrict__ ssrc, int* __restrict__ sdst)
{
    int e = blockIdx.x * 256 + threadIdx.x;
    int s = pidx[2 * e], d = pidx[2 * e + 1];
    unsigned pos = atomicAdd(&cur[s], 1u);
    sid[pos] = e;
    ssrc[pos] = s << 10;
    sdst[pos] = (d << 10) + 512;
}

// ===== C = ef @ K_bot via MFMA (hi/lo), gather-read / linear-write; xL2E-scaled =====
__global__ void __launch_bounds__(512) edge_c_mfma(
    const float* __restrict__ ef, const float* __restrict__ Ks,
    const float* __restrict__ Kg, const int* __restrict__ sid,
    unsigned* __restrict__ C32)
{
    __shared__ short As_h[64 * 64];
    __shared__ short As_l[64 * 64];
    const int t = threadIdx.x;
    const int w = t >> 6, lane = t & 63;

    union U8 { short s[8]; bf16x8 v; };
    bf16x8 bS[2][2], bG[2][2];
    {
        const int col = w * 16 + (lane & 15);
#pragma unroll
        for (int ki = 0; ki < 2; ++ki) {
            U8 sh_, sl_, gh_, gl_;
            const int kbase = 2 * AD + ki * 32 + (lane >> 4) * 8;
#pragma unroll
            for (int j = 0; j < 8; ++j) {
                float vs = Ks[(size_t)(kbase + j) * AD + col];
                float vg = Kg[(size_t)(kbase + j) * AD + col];
                unsigned short h = bf16_rne(vs);
                sh_.s[j] = (short)h;
                sl_.s[j] = (short)bf16_rne(vs - __uint_as_float((unsigned)h << 16));
                h = bf16_rne(vg);
                gh_.s[j] = (short)h;
                gl_.s[j] = (short)bf16_rne(vg - __uint_as_float((unsigned)h << 16));
            }
            bS[ki][0] = sh_.v; bS[ki][1] = sl_.v;
            bG[ki][0] = gh_.v; bG[ki][1] = gl_.v;
        }
    }

    const int srow = t >> 4, sc4 = t & 15;
    f32x4 pf0, pf1;
    {
        int ea = sid[(size_t)blockIdx.x * 64 + srow];
        int eb = sid[(size_t)blockIdx.x * 64 + srow + 32];
        pf0 = __builtin_nontemporal_load((const f32x4*)&ef[(size_t)ea * 64 + 4 * sc4]);
        pf1 = __builtin_nontemporal_load((const f32x4*)&ef[(size_t)eb * 64 + 4 * sc4]);
    }

    for (int tile = blockIdx.x; tile < NTILES; tile += gridDim.x) {
        __syncthreads();
        {
            f32x4 v[2] = {pf0, pf1};
#pragma unroll
            for (int ii = 0; ii < 2; ++ii) {
                int row = srow + 32 * ii;
                float a0 = v[ii][0], a1 = v[ii][1], a2 = v[ii][2], a3 = v[ii][3];
                unsigned short h0 = bf16_rne(a0), h1 = bf16_rne(a1),
                               h2 = bf16_rne(a2), h3 = bf16_rne(a3);
                unsigned short l0 = bf16_rne(a0 - __uint_as_float((unsigned)h0 << 16));
                unsigned short l1 = bf16_rne(a1 - __uint_as_float((unsigned)h1 << 16));
                unsigned short l2 = bf16_rne(a2 - __uint_as_float((unsigned)h2 << 16));
                unsigned short l3 = bf16_rne(a3 - __uint_as_float((unsigned)h3 << 16));
                int sidx = (row * 64 + sc4 * 4) ^ ((row & 7) << 3);
                *(short4*)&As_h[sidx] = make_short4((short)h0, (short)h1, (short)h2, (short)h3);
                *(short4*)&As_l[sidx] = make_short4((short)l0, (short)l1, (short)l2, (short)l3);
            }
        }
        {
            int nxt = tile + gridDim.x;
            if (nxt < NTILES) {
                int ea = sid[(size_t)nxt * 64 + srow];
                int eb = sid[(size_t)nxt * 64 + srow + 32];
                pf0 = __builtin_nontemporal_load((const f32x4*)&ef[(size_t)ea * 64 + 4 * sc4]);
                pf1 = __builtin_nontemporal_load((const f32x4*)&ef[(size_t)eb * 64 + 4 * sc4]);
            }
        }
        __syncthreads();

        f32x4 accS[4] = {}, accG[4] = {};
#pragma unroll
        for (int mt = 0; mt < 4; ++mt) {
#pragma unroll
            for (int ki = 0; ki < 2; ++ki) {
                int row = mt * 16 + (lane & 15);
                int idx = (row * 64 + ki * 32 + (lane >> 4) * 8) ^ ((row & 7) << 3);
                bf16x8 ah = *(const bf16x8*)&As_h[idx];
                bf16x8 al = *(const bf16x8*)&As_l[idx];
                accS[mt] = __builtin_amdgcn_mfma_f32_16x16x32_bf16(ah, bS[ki][0], accS[mt], 0, 0, 0);
                accS[mt] = __builtin_amdgcn_mfma_f32_16x16x32_bf16(al, bS[ki][0], accS[mt], 0, 0, 0);
                accS[mt] = __builtin_amdgcn_mfma_f32_16x16x32_bf16(ah, bS[ki][1], accS[mt], 0, 0, 0);
                accG[mt] = __builtin_amdgcn_mfma_f32_16x16x32_bf16(ah, bG[ki][0], accG[mt], 0, 0, 0);
                accG[mt] = __builtin_amdgcn_mfma_f32_16x16x32_bf16(al, bG[ki][0], accG[mt], 0, 0, 0);
                accG[mt] = __builtin_amdgcn_mfma_f32_16x16x32_bf16(ah, bG[ki][1], accG[mt], 0, 0, 0);
            }
        }
        const size_t p0 = (size_t)tile * 64;
#pragma unroll
        for (int mt = 0; mt < 4; ++mt) {
#pragma unroll
            for (int reg = 0; reg < 4; ++reg) {
                int row = mt * 16 + (lane >> 4) * 4 + reg;
                unsigned val = pack_bf2(accS[mt][reg] * L2E, accG[mt][reg] * L2E);
                __builtin_nontemporal_store(val,
                    &C32[(p0 + row) * 128 + w * 16 + (lane & 15)]);
            }
        }
    }
}

// ===== sorted apply v4: log2-domain, readlane-scalarized, zero LDS =====
__global__ void __launch_bounds__(256) edge_apply_sorted(
    const char* __restrict__ C8, const char* __restrict__ PQ8,
    const int* __restrict__ ssrcS, const int* __restrict__ sdstS,
    const float* __restrict__ bs, const float* __restrict__ bg,
    float* __restrict__ acc)
{
    const int t = threadIdx.x & 63;
    const int w = threadIdx.x >> 6;
    const size_t p0 = ((size_t)blockIdx.x * 4 + w) * 64;
    const int srcv = ssrcS[p0 + t];      // lane i holds byte-off of edge p0+i
    const int dstv = sdstS[p0 + t];

    const float2 bsv = *(const float2*)&bs[2 * t];
    const float2 bgv = *(const float2*)&bg[2 * t];
    const float bsA = bsv.x * L2E, bsB = bsv.y * L2E;
    const float bgA = bgv.x * L2E, bgB = bgv.y * L2E;

    const char* PQl = PQ8 + 8 * t;
    char* accl = (char*)acc + 8 * t;
    const char* Cl = C8 + p0 * 512 + 8 * t;

#define RL(v, i) __builtin_amdgcn_readlane((v), (i))
#define LOADC(i) __builtin_nontemporal_load((const u32x2*)(Cl + (i) * 512))
#define LOADQ(i) (*(const u32x2*)(PQl + RL(dstv, (i))))
#define LOADP(s_) (*(const u32x2*)(PQl + (s_)))

    int cur = RL(srcv, 0);
    u32x2 pv = LOADP(cur);
    float psA = unp_lo(pv.x) + bsA, pgA = unp_hi(pv.x) + bgA;
    float psB = unp_lo(pv.y) + bsB, pgB = unp_hi(pv.y) + bgB;

    u32x2 c0 = LOADC(0), c1 = LOADC(1), c2 = LOADC(2), c3 = LOADC(3);
    u32x2 q0 = LOADQ(0), q1 = LOADQ(1), q2 = LOADQ(2), q3 = LOADQ(3);
    u32x2 r0 = pv, r1 = pv, r2 = pv, r3 = pv;
    if (RL(srcv, 1) != RL(srcv, 0)) r1 = LOADP(RL(srcv, 1));
    if (RL(srcv, 2) != RL(srcv, 1)) r2 = LOADP(RL(srcv, 2));
    if (RL(srcv, 3) != RL(srcv, 2)) r3 = LOADP(RL(srcv, 3));
    float accA = 0.f, accB = 0.f;

#define FLUSH                                                              \
    atomicAdd((float*)(accl + ((unsigned)cur >> 1)),     LN2 * accA);      \
    atomicAdd((float*)(accl + ((unsigned)cur >> 1) + 4), LN2 * accB);

#define CORE(i, cc, qq, rr)                                                \
    {                                                                      \
        int src_ = RL(srcv, (i));                                          \
        if (src_ != cur) {                                                 \
            FLUSH;                                                         \
            accA = 0.f; accB = 0.f; cur = src_;                            \
            psA = unp_lo(rr.x) + bsA; pgA = unp_hi(rr.x) + bgA;            \
            psB = unp_lo(rr.y) + bsB; pgB = unp_hi(rr.y) + bgB;            \
        }                                                                  \
        float sA = unp_lo(cc.x) + unp_lo(qq.x) + psA;                      \
        float gA = unp_hi(cc.x) + unp_hi(qq.x) + pgA;                      \
        float sB = unp_lo(cc.y) + unp_lo(qq.y) + psB;                      \
        float gB = unp_hi(cc.y) + unp_hi(qq.y) + pgB;                      \
        float spA = fmaxf(gA, 0.f) + log2_f(1.f + nexp2_abs_f(gA));        \
        float spB = fmaxf(gB, 0.f) + log2_f(1.f + nexp2_abs_f(gB));       \
        accA = fmaf(__builtin_amdgcn_rcpf(1.f + nexp2_f(sA)), spA, accA);  \
        accB = fmaf(__builtin_amdgcn_rcpf(1.f + nexp2_f(sB)), spB, accB);  \
    }

#define STEP(i, cc, qq, rr)                                                \
    CORE(i, cc, qq, rr)                                                    \
    {                                                                      \
        cc = LOADC((i) + 4);                                               \
        qq = LOADQ((i) + 4);                                               \
        if (RL(srcv, (i) + 4) != RL(srcv, (i) + 3))                        \
            rr = LOADP(RL(srcv, (i) + 4));                                 \
    }

    for (int b = 0; b < 60; b += 4) {
        STEP(b + 0, c0, q0, r0)
        STEP(b + 1, c1, q1, r1)
        STEP(b + 2, c2, q2, r2)
        STEP(b + 3, c3, q3, r3)
    }
    CORE(60, c0, q0, r0)
    CORE(61, c1, q1, r1)
    CORE(62, c2, q2, r2)
    CORE(63, c3, q3, r3)
    FLUSH;

#undef STEP
#undef CORE
#undef FLUSH
#undef LOADP
#undef LOADQ
#undef LOADC
#undef RL
}

// ===== final softplus =====
__global__ void __launch_bounds__(256) act_k(float* __restrict__ acc)
{
    size_t i = ((size_t)blockIdx.x * 256 + threadIdx.x) * 4;
    float4 v = *(float4*)&acc[i];
    v.x = softplus_f(v.x);
    v.y = softplus_f(v.y);
    v.z = softplus_f(v.z);
    v.w = softplus_f(v.w);
    *(float4*)&acc[i] = v;
}

// ===== Tier B fallback (round-1, known good) =====
__global__ void __launch_bounds__(128) node_mm_f32(
    const float* __restrict__ x, const float* __restrict__ Ks,
    const float* __restrict__ Kg, float* __restrict__ PQ)
{
    __shared__ float xs[8][AD];
    const int t = threadIdx.x;
    const int row0 = blockIdx.x * 8;
#pragma unroll
    for (int r = 0; r < 8; ++r) xs[r][t] = x[(size_t)(row0 + r) * AD + t];
    __syncthreads();
    float aPs[8] = {}, aQs[8] = {}, aPg[8] = {}, aQg[8] = {};
    for (int k = 0; k < AD; ++k) {
        float ks_s = Ks[k * AD + t];
        float ks_d = Ks[(AD + k) * AD + t];
        float kg_s = Kg[k * AD + t];
        float kg_d = Kg[(AD + k) * AD + t];
#pragma unroll
        for (int r = 0; r < 8; ++r) {
            float xv = xs[r][k];
            aPs[r] = fmaf(xv, ks_s, aPs[r]);
            aQs[r] = fmaf(xv, ks_d, aQs[r]);
            aPg[r] = fmaf(xv, kg_s, aPg[r]);
            aQg[r] = fmaf(xv, kg_d, aQg[r]);
        }
    }
#pragma unroll
    for (int r = 0; r < 8; ++r) {
        float* o = PQ + (size_t)(row0 + r) * 512;
        *(float2*)&o[2 * t]       = make_float2(aPs[r], aPg[r]);
        *(float2*)&o[256 + 2 * t] = make_float2(aQs[r], aQg[r]);
    }
}

__global__ void __launch_bounds__(256) edge_fused(
    const float* __restrict__ ef, const float* __restrict__ Ks,
    const float* __restrict__ Kg, const float* __restrict__ PQ,
    const int* __restrict__ pidx, const float* __restrict__ bs,
    const float* __restrict__ bg, float* __restrict__ acc)
{
    __shared__ float KB[ED][2 * AD];
    __shared__ float es[64][ED];
    const int t = threadIdx.x;
    for (int i = t; i < ED * AD; i += 256) {
        int k = i >> 7, n = i & 127;
        KB[k][2 * n]     = Ks[(2 * AD + k) * AD + n];
        KB[k][2 * n + 1] = Kg[(2 * AD + k) * AD + n];
    }
    const size_t e0 = (size_t)blockIdx.x * 64;
    for (int i = t; i < 64 * ED; i += 256) ((float*)es)[i] = ef[e0 * ED + i];
    __syncthreads();
    const int le = t >> 7, n = t & 127;
    const float bsn = bs[n], bgn = bg[n];
    for (int base = le * 8; base < 64; base += 16) {
        float accS[8] = {}, accG[8] = {};
        for (int k4 = 0; k4 < ED / 4; ++k4) {
            float2 kv0 = *(const float2*)&KB[4 * k4 + 0][2 * n];
            float2 kv1 = *(const float2*)&KB[4 * k4 + 1][2 * n];
            float2 kv2 = *(const float2*)&KB[4 * k4 + 2][2 * n];
            float2 kv3 = *(const float2*)&KB[4 * k4 + 3][2 * n];
#pragma unroll
            for (int r = 0; r < 8; ++r) {
                float4 ev = *(const float4*)&es[base + r][4 * k4];
                accS[r] = fmaf(ev.x, kv0.x, accS[r]);
                accG[r] = fmaf(ev.x, kv0.y, accG[r]);
                accS[r] = fmaf(ev.y, kv1.x, accS[r]);
                accG[r] = fmaf(ev.y, kv1.y, accG[r]);
                accS[r] = fmaf(ev.z, kv2.x, accS[r]);
                accG[r] = fmaf(ev.z, kv2.y, accG[r]);
                accS[r] = fmaf(ev.w, kv3.x, accS[r]);
                accG[r] = fmaf(ev.w, kv3.y, accG[r]);
            }
        }
#pragma unroll
        for (int r = 0; r < 8; ++r) {
            size_t e = e0 + base + r;
            int src = pidx[2 * e], dst = pidx[2 * e + 1];
            float2 pv = *(const float2*)&PQ[(size_t)src * 512 + 2 * n];
            float2 qv = *(const float2*)&PQ[(size_t)dst * 512 + 256 + 2 * n];
            float s = accS[r] + pv.x + qv.x + bsn;
            float g = accG[r] + pv.y + qv.y + bgn;
            atomicAdd(&acc[(size_t)src * AD + n], sigmoid_fast(s) * softplus_f(g));
        }
    }
}

// ===== launch =====
extern "C" void kernel_launch(void* const* d_in, const int* in_sizes, int n_in,
                              void* d_out, int out_size, void* d_ws, size_t ws_size,
                              hipStream_t stream)
{
    const float* atom = (const float*)d_in[0];
    const float* ef   = (const float*)d_in[1];
    const float* Ks   = (const float*)d_in[3];
    const float* bs   = (const float*)d_in[4];
    const float* Kg   = (const float*)d_in[5];
    const float* bg   = (const float*)d_in[6];
    const int*   pidx = (const int*)d_in[7];

    float* acc = (float*)d_out;

    char* w = (char*)d_ws;
    const size_t PQ_B   = (size_t)NN * 256 * 4;   //  51.2 MB
    const size_t C_B    = (size_t)NE * 128 * 4;   // 409.6 MB
    const size_t BN_B   = 16384 * 16;             // 256 KB
    const size_t CNT_B  = (size_t)NN * 4;
    const size_t IDX_B  = (size_t)NE * 4;
    const size_t PART_B = 256 * 4;
    unsigned* PQ32 = (unsigned*)w;  w += PQ_B;
    unsigned* C32  = (unsigned*)w;  w += C_B;
    bf16x8*   Bn   = (bf16x8*)w;    w += BN_B;
    unsigned* cnt  = (unsigned*)w;  w += CNT_B;
    unsigned* curp = (unsigned*)w;  w += CNT_B;
    int*      sid  = (int*)w;       w += IDX_B;
    int*      ssrc = (int*)w;       w += IDX_B;
    int*      sdst = (int*)w;       w += IDX_B;
    unsigned* part = (unsigned*)w;  w += PART_B;
    const size_t TOTAL_A = PQ_B + C_B + BN_B + 2 * CNT_B + 3 * IDX_B + PART_B;

    if (ws_size >= TOTAL_A) {
        hipMemsetAsync(cnt, 0, CNT_B, stream);
        bn_prep<<<64, 256, 0, stream>>>(Ks, Kg, Bn);
        hist_k<<<NE / 256, 256, 0, stream>>>(pidx, cnt);
        scan1_k<<<NSCAN, 256, 0, stream>>>(cnt, curp, part);
        scan2_k<<<1, 256, 0, stream>>>(part);
        scan3_k<<<NSCAN, 256, 0, stream>>>(curp, part);
        scatter_k<<<NE / 256, 256, 0, stream>>>(pidx, curp, sid, ssrc, sdst);
        edge_c_mfma<<<2048, 512, 0, stream>>>(ef, Ks, Kg, sid, C32);

        for (int s = 0; s < NSTEPS; ++s) {
            node_mm_mfma<<<NROWB, 512, 0, stream>>>(atom, acc, Bn, PQ32,
                                                    s == 0 ? 0 : 1);
            edge_apply_sorted<<<NE / 256, 256, 0, stream>>>(
                (const char*)C32, (const char*)PQ32, ssrc, sdst, bs, bg, acc);
        }
        act_k<<<(NN * AD) / 1024, 256, 0, stream>>>(acc);
    } else {
        float* PQ = (float*)d_ws;
        hipMemcpyAsync(acc, atom, (size_t)NN * AD * sizeof(float),
                       hipMemcpyDeviceToDevice, stream);
        for (int s = 0; s < NSTEPS; ++s) {
            node_mm_f32<<<NN / 8, 128, 0, stream>>>(acc, Ks, Kg, PQ);
            edge_fused<<<NE / 64, 256, 0, stream>>>(ef, Ks, Kg, PQ, pidx, bs, bg, acc);
            act_k<<<(NN * AD) / 1024, 256, 0, stream>>>(acc);
        }
    }
}